// Round 1
// baseline (2313.475 us; speedup 1.0000x reference)
//
#include <hip/hip_runtime.h>
#include <hip/hip_bf16.h>
#include <math.h>

// Problem constants (fixed by setup_inputs)
constexpr int B    = 4;
constexpr int D    = 768;
constexpr int HW   = 1024;          // 32*32
constexpr int M    = B * HW;        // 4096 queries
constexpr int NDB  = 20000;
constexpr int KNN  = 3;
constexpr int OUTH = 512;
constexpr int OUTW = 512;

constexpr int QT = 64;              // queries per block tile
constexpr int NT = 64;              // db rows per tile
constexpr int KC = 16;              // K chunk
constexpr int NS = 8;               // N splits (grid.y)
constexpr int NTILES = (NDB + NT - 1) / NT;   // 313

__device__ __forceinline__ void insert3(float& t0, float& t1, float& t2, float d) {
    // branchless sorted-insert into 3 smallest (t0 <= t1 <= t2)
    float a0 = fminf(d, t0);
    float b0 = fmaxf(d, t0);
    float a1 = fminf(b0, t1);
    float b1 = fmaxf(b0, t1);
    t0 = a0;
    t1 = a1;
    t2 = fminf(b1, t2);
}

// ---------------------------------------------------------------------------
// 1) db row squared norms: x2[n] = sum_d db[n][d]^2
__global__ __launch_bounds__(256) void db_norms(const float* __restrict__ db,
                                                float* __restrict__ x2) {
    int wave = threadIdx.x >> 6;
    int lane = threadIdx.x & 63;
    int n = blockIdx.x * 4 + wave;
    if (n >= NDB) return;
    const float4* row = (const float4*)(db + (size_t)n * D);   // 192 float4
    float s = 0.f;
    #pragma unroll
    for (int j = 0; j < 3; ++j) {
        float4 v = row[lane + j * 64];
        s += v.x * v.x + v.y * v.y + v.z * v.z + v.w * v.w;
    }
    #pragma unroll
    for (int off = 32; off > 0; off >>= 1) s += __shfl_down(s, off);
    if (lane == 0) x2[n] = s;
}

// ---------------------------------------------------------------------------
// 2) query squared norms: q2[m] = sum_d emb[b][d][p]^2  (m = b*1024 + p)
__global__ __launch_bounds__(256) void q_norms(const float* __restrict__ emb,
                                               float* __restrict__ q2) {
    __shared__ float red[4][QT];
    int t = threadIdx.x;
    int p = t & 63;                  // query within block
    int dg = t >> 6;                 // d-group 0..3 (192 d each)
    int m0 = blockIdx.x * 64;        // 64 blocks
    int m = m0 + p;
    int b = m >> 10;
    int pp = m & 1023;
    const float* base = emb + (size_t)b * D * HW + pp;
    float s = 0.f;
    #pragma unroll 8
    for (int d = dg * 192; d < dg * 192 + 192; ++d) {
        float v = base[(size_t)d * HW];
        s = fmaf(v, v, s);
    }
    red[dg][p] = s;
    __syncthreads();
    if (t < 64) q2[m0 + t] = red[0][t] + red[1][t] + red[2][t] + red[3][t];
}

// ---------------------------------------------------------------------------
// 3) fused GEMM + top-3 of score s = x2[n] - 2*dot(q,x)
//    grid: (64 qtiles, NS splits), block 256.
//    Each thread owns a 4x4 sub-tile: rows tr*4.., cols tc*4..
__global__ __launch_bounds__(256) void gemm_topk(const float* __restrict__ emb,
                                                 const float* __restrict__ db,
                                                 const float* __restrict__ x2,
                                                 float* __restrict__ partials) {
    __shared__ float As[KC][QT];      // [k][m] 4 KB
    __shared__ float Bs[KC][NT];      // [k][n] 4 KB
    __shared__ float X2s[NT];
    __shared__ float red[QT][16][3];  // 12 KB

    const int t  = threadIdx.x;
    const int qt = blockIdx.x;        // 0..63
    const int sp = blockIdx.y;        // 0..NS-1
    const int m0 = qt * QT;
    const int b  = m0 >> 10;          // QT divides 1024 -> whole tile in one batch
    const int p0 = m0 & 1023;
    const float* embB = emb + (size_t)b * D * HW;

    const int tr = t >> 4;            // 0..15
    const int tc = t & 15;            // 0..15

    float t0[4], t1[4], t2v[4];
    #pragma unroll
    for (int i = 0; i < 4; ++i) { t0[i] = INFINITY; t1[i] = INFINITY; t2v[i] = INFINITY; }

    // staging thread mappings
    const int a_kk = t >> 4, a_pg = t & 15;     // A: [kk][pg*4..+3]
    const int b_n  = t >> 2, b_kq = t & 3;      // B: row n, k-quad kq

    for (int tile = sp; tile < NTILES; tile += NS) {
        const int n0 = tile * NT;

        float acc[4][4];
        #pragma unroll
        for (int i = 0; i < 4; ++i)
            #pragma unroll
            for (int j = 0; j < 4; ++j) acc[i][j] = 0.f;

        for (int k0 = 0; k0 < D; k0 += KC) {
            __syncthreads();   // protects As/Bs reuse and X2s readers of prev tile
            // stage A chunk: As[kk][p] = Q[m0+p][k0+kk] (coalesced: contiguous p)
            {
                float4 v = *(const float4*)(embB + (size_t)(k0 + a_kk) * HW + p0 + a_pg * 4);
                *(float4*)(&As[a_kk][a_pg * 4]) = v;
            }
            // stage B chunk (transposed): Bs[k][n] = db[n0+n][k0+k]
            {
                int gn = n0 + b_n;
                float4 v = make_float4(0.f, 0.f, 0.f, 0.f);
                if (gn < NDB) v = *(const float4*)(db + (size_t)gn * D + k0 + b_kq * 4);
                Bs[b_kq * 4 + 0][b_n] = v.x;
                Bs[b_kq * 4 + 1][b_n] = v.y;
                Bs[b_kq * 4 + 2][b_n] = v.z;
                Bs[b_kq * 4 + 3][b_n] = v.w;
            }
            if (k0 == 0 && t < NT) {
                int gn = n0 + t;
                X2s[t] = (gn < NDB) ? x2[gn] : INFINITY;
            }
            __syncthreads();

            #pragma unroll
            for (int k = 0; k < KC; ++k) {
                float a[4], bv[4];
                *(float4*)a  = *(const float4*)&As[k][tr * 4];
                *(float4*)bv = *(const float4*)&Bs[k][tc * 4];
                #pragma unroll
                for (int i = 0; i < 4; ++i)
                    #pragma unroll
                    for (int j = 0; j < 4; ++j)
                        acc[i][j] = fmaf(a[i], bv[j], acc[i][j]);
            }
        }

        // score + top-3 update (X2s valid; next tile's first sync protects it)
        #pragma unroll
        for (int j = 0; j < 4; ++j) {
            float xx = X2s[tc * 4 + j];
            #pragma unroll
            for (int i = 0; i < 4; ++i) {
                float s = fmaf(-2.f, acc[i][j], xx);
                insert3(t0[i], t1[i], t2v[i], s);
            }
        }
    }

    // cross-thread top-3 merge per row
    __syncthreads();
    #pragma unroll
    for (int i = 0; i < 4; ++i) {
        red[tr * 4 + i][tc][0] = t0[i];
        red[tr * 4 + i][tc][1] = t1[i];
        red[tr * 4 + i][tc][2] = t2v[i];
    }
    __syncthreads();
    if (t < QT) {
        float a0 = INFINITY, a1 = INFINITY, a2 = INFINITY;
        #pragma unroll
        for (int c = 0; c < 16; ++c) {
            insert3(a0, a1, a2, red[t][c][0]);
            insert3(a0, a1, a2, red[t][c][1]);
            insert3(a0, a1, a2, red[t][c][2]);
        }
        float* dst = partials + ((size_t)(m0 + t) * NS + sp) * 3;
        dst[0] = a0; dst[1] = a1; dst[2] = a2;
    }
}

// ---------------------------------------------------------------------------
// 4) merge partial top-3 across splits, add q2, sqrt, mean -> ood[4][32][32]
__global__ __launch_bounds__(256) void merge_ood(const float* __restrict__ partials,
                                                 const float* __restrict__ q2,
                                                 float* __restrict__ ood) {
    int m = blockIdx.x * 256 + threadIdx.x;   // 16 blocks
    if (m >= M) return;
    const float* pp = partials + (size_t)m * NS * 3;
    float a0 = INFINITY, a1 = INFINITY, a2 = INFINITY;
    #pragma unroll
    for (int j = 0; j < NS * 3; ++j) insert3(a0, a1, a2, pp[j]);
    float q = q2[m];
    float d0 = sqrtf(fmaxf(q + a0, 1e-12f));
    float d1 = sqrtf(fmaxf(q + a1, 1e-12f));
    float d2 = sqrtf(fmaxf(q + a2, 1e-12f));
    ood[m] = (d0 + d1 + d2) * (1.f / 3.f);
}

// ---------------------------------------------------------------------------
// 5) half-pixel bilinear 32x32 -> 512x512 (align_corners=False semantics;
//    edge renormalization == clamp here, verified analytically)
__global__ __launch_bounds__(256) void upsample(const float* __restrict__ ood,
                                                float* __restrict__ out) {
    int idx = blockIdx.x * 256 + threadIdx.x;     // 4096 blocks -> 1,048,576
    int ox = idx & (OUTW - 1);
    int oy = (idx >> 9) & (OUTH - 1);
    int bb = idx >> 18;
    float sx = (ox + 0.5f) * (32.f / OUTW) - 0.5f;
    float sy = (oy + 0.5f) * (32.f / OUTH) - 0.5f;
    float fx = floorf(sx), fy = floorf(sy);
    float wx = sx - fx, wy = sy - fy;
    int x0 = max(0, min(31, (int)fx));
    int x1 = max(0, min(31, (int)fx + 1));
    int y0 = max(0, min(31, (int)fy));
    int y1 = max(0, min(31, (int)fy + 1));
    const float* src = ood + bb * 1024;
    float v00 = src[y0 * 32 + x0];
    float v01 = src[y0 * 32 + x1];
    float v10 = src[y1 * 32 + x0];
    float v11 = src[y1 * 32 + x1];
    float top = v00 + wx * (v01 - v00);
    float bot = v10 + wx * (v11 - v10);
    out[idx] = top + wy * (bot - top);
}

// ---------------------------------------------------------------------------
extern "C" void kernel_launch(void* const* d_in, const int* in_sizes, int n_in,
                              void* d_out, int out_size, void* d_ws, size_t ws_size,
                              hipStream_t stream) {
    const float* emb = (const float*)d_in[0];   // [4][768][32][32]
    const float* db  = (const float*)d_in[1];   // [20000][768]
    float* out = (float*)d_out;                 // [4][1][512][512]

    // workspace layout (floats): total ~506 KB
    float* ws       = (float*)d_ws;
    float* x2       = ws;                 // 20000
    float* q2       = ws + 20000;         // 4096
    float* ood      = ws + 24096;         // 4096
    float* partials = ws + 28192;         // 4096 * NS * 3 = 98304

    db_norms<<<(NDB + 3) / 4, 256, 0, stream>>>(db, x2);
    q_norms<<<M / 64, 256, 0, stream>>>(emb, q2);
    gemm_topk<<<dim3(M / QT, NS), 256, 0, stream>>>(emb, db, x2, partials);
    merge_ood<<<(M + 255) / 256, 256, 0, stream>>>(partials, q2, ood);
    upsample<<<(B * OUTH * OUTW) / 256, 256, 0, stream>>>(ood, out);
}

// Round 2
// 356.328 us; speedup vs baseline: 6.4925x; 6.4925x over previous
//
#include <hip/hip_runtime.h>
#include <hip/hip_bf16.h>
#include <math.h>

// Problem constants
constexpr int B    = 4;
constexpr int D    = 768;
constexpr int HW   = 1024;
constexpr int M    = B * HW;        // 4096 queries
constexpr int NDB  = 20000;
constexpr int NDBP = 20096;         // padded to 157*128
constexpr int OUTH = 512;
constexpr int OUTW = 512;

constexpr int KAUG   = 800;         // 768 + 2 aug cols + pad to 25*32
constexpr int BM     = 128;         // db rows per tile
constexpr int BN     = 128;         // queries per tile
constexpr int BK     = 32;
constexpr int KSTEPS = KAUG / BK;   // 25
constexpr int NSPLIT = 24;
constexpr int NT2    = NDBP / BM;   // 157

typedef unsigned short ushort_t;
typedef __bf16 bf16x8 __attribute__((ext_vector_type(8)));
typedef float  f32x4  __attribute__((ext_vector_type(4)));

__device__ __forceinline__ unsigned short f2bf(float x) {
    union { __hip_bfloat16 h; unsigned short s; } c;
    c.h = __float2bfloat16(x);
    return c.s;
}
__device__ __forceinline__ float bf2f(unsigned short u) {
    union { unsigned short s[2]; float f; } c;
    c.s[0] = 0; c.s[1] = u;
    return c.f;
}

__device__ __forceinline__ void insert3(float& t0, float& t1, float& t2, float d) {
    float a0 = fminf(d, t0);
    float b0 = fmaxf(d, t0);
    float a1 = fminf(b0, t1);
    float b1 = fmaxf(b0, t1);
    t0 = a0; t1 = a1;
    t2 = fminf(b1, t2);
}

union P8 { unsigned short u[8]; uint4 v; };

__device__ __forceinline__ void gl_lds16(const unsigned short* g, unsigned short* l) {
    __builtin_amdgcn_global_load_lds(
        (const __attribute__((address_space(1))) void*)g,
        (__attribute__((address_space(3))) void*)l, 16, 0, 0);
}

// ---------------------------------------------------------------------------
// 1) db -> bf16 [20096][800], chunk-XOR-swizzled, aug cols 768/769 = x2 hi/lo.
//    Pad rows: zero except x2 col = 1e30. One wave per row.
__global__ __launch_bounds__(256) void db_convert(const float* __restrict__ db,
                                                  unsigned short* __restrict__ dbb) {
    int wave = threadIdx.x >> 6;
    int lane = threadIdx.x & 63;
    int n = blockIdx.x * 4 + wave;
    if (n >= NDBP) return;
    unsigned short* out = dbb + (size_t)n * KAUG;
    int nx = n & 3;

    if (n >= NDB) {   // pad row
        #pragma unroll
        for (int pass = 0; pass < 2; ++pass) {
            int c = lane + pass * 64;
            if (c < 100) {
                P8 pk; pk.v = make_uint4(0, 0, 0, 0);
                if (c == 96) pk.u[0] = f2bf(1e30f);
                *(uint4*)(out + (c >> 2) * 32 + ((c & 3) ^ nx) * 8) = pk.v;
            }
        }
        return;
    }

    const float4* row = (const float4*)(db + (size_t)n * D);   // 192 float4
    float s = 0.f;
    #pragma unroll
    for (int j = 0; j < 3; ++j) {
        float4 v = row[lane + j * 64];
        s += v.x * v.x + v.y * v.y + v.z * v.z + v.w * v.w;
    }
    #pragma unroll
    for (int m = 1; m < 64; m <<= 1) s += __shfl_xor(s, m);

    // convert chunks 0..95 (8 floats each)
    auto do_chunk = [&](int c) {
        float4 v0 = row[c * 2];
        float4 v1 = row[c * 2 + 1];
        P8 pk;
        pk.u[0] = f2bf(v0.x); pk.u[1] = f2bf(v0.y); pk.u[2] = f2bf(v0.z); pk.u[3] = f2bf(v0.w);
        pk.u[4] = f2bf(v1.x); pk.u[5] = f2bf(v1.y); pk.u[6] = f2bf(v1.z); pk.u[7] = f2bf(v1.w);
        *(uint4*)(out + (c >> 2) * 32 + ((c & 3) ^ nx) * 8) = pk.v;
    };
    do_chunk(lane);
    if (lane < 32) {
        do_chunk(64 + lane);
    } else if (lane < 36) {
        int c = 96 + (lane - 32);
        P8 pk; pk.v = make_uint4(0, 0, 0, 0);
        if (c == 96) {
            unsigned short hi = f2bf(s);
            float lo = s - bf2f(hi);
            pk.u[0] = hi;
            pk.u[1] = f2bf(lo);
        }
        *(uint4*)(out + (c >> 2) * 32 + ((c & 3) ^ nx) * 8) = pk.v;
    }
}

// ---------------------------------------------------------------------------
// 2) emb [4][768][1024] -> qb bf16 [4096][800] (transpose, scale -2, swizzle)
__global__ __launch_bounds__(256) void q_transpose(const float* __restrict__ emb,
                                                   unsigned short* __restrict__ qb) {
    __shared__ float tile[64][65];
    int b  = blockIdx.z;
    int kt = blockIdx.y;    // 0..11
    int pt = blockIdx.x;    // 0..15
    int t  = threadIdx.x;
    const float* src = emb + ((size_t)b * D + kt * 64) * HW + pt * 64;
    #pragma unroll
    for (int pass = 0; pass < 4; ++pass) {
        int kl = (t >> 4) + pass * 16;
        int pl = (t & 15) * 4;
        float4 v = *(const float4*)(src + (size_t)kl * HW + pl);
        tile[kl][pl + 0] = v.x; tile[kl][pl + 1] = v.y;
        tile[kl][pl + 2] = v.z; tile[kl][pl + 3] = v.w;
    }
    __syncthreads();
    #pragma unroll
    for (int pass = 0; pass < 2; ++pass) {
        int p  = (t >> 3) + pass * 32;
        int cl = t & 7;
        int m  = b * HW + pt * 64 + p;
        P8 pk;
        #pragma unroll
        for (int j = 0; j < 8; ++j) pk.u[j] = f2bf(-2.f * tile[cl * 8 + j][p]);
        int c = kt * 8 + cl;
        *(uint4*)(qb + (size_t)m * KAUG + (c >> 2) * 32 + ((c & 3) ^ (m & 3)) * 8) = pk.v;
    }
}

// 2b) qb aug cols: chunk 96 = [1,1,0,...], chunks 97..99 = 0
__global__ __launch_bounds__(256) void q_aug(unsigned short* __restrict__ qb) {
    int id = blockIdx.x * 256 + threadIdx.x;   // 16384
    int m = id >> 2, c4 = id & 3;
    P8 pk; pk.v = make_uint4(0, 0, 0, 0);
    if (c4 == 0) { pk.u[0] = f2bf(1.f); pk.u[1] = f2bf(1.f); }
    *(uint4*)(qb + (size_t)m * KAUG + 24 * 32 + (c4 ^ (m & 3)) * 8) = pk.v;
}

// ---------------------------------------------------------------------------
// 3) query squared norms (fp32 exact)
__global__ __launch_bounds__(256) void q_norms(const float* __restrict__ emb,
                                               float* __restrict__ q2) {
    __shared__ float red[4][64];
    int t = threadIdx.x;
    int p = t & 63;
    int dg = t >> 6;
    int m0 = blockIdx.x * 64;
    int m = m0 + p;
    int b = m >> 10;
    int pp = m & 1023;
    const float* base = emb + (size_t)b * D * HW + pp;
    float s = 0.f;
    #pragma unroll 8
    for (int d = dg * 192; d < dg * 192 + 192; ++d) {
        float v = base[(size_t)d * HW];
        s = fmaf(v, v, s);
    }
    red[dg][p] = s;
    __syncthreads();
    if (t < 64) q2[m0 + t] = red[0][t] + red[1][t] + red[2][t] + red[3][t];
}

// ---------------------------------------------------------------------------
// 4) MFMA GEMM + fused running top-3.
//    C[n][m] = x2[n] - 2*db[n].q[m] via K-augmentation. A=db rows, B=queries.
__global__ __launch_bounds__(256, 3) void gemm_topk(const unsigned short* __restrict__ dbb,
                                                    const unsigned short* __restrict__ qb,
                                                    float* __restrict__ partials) {
    __shared__ __align__(16) unsigned short As[BM * BK];   // 8KB, row n at n*32
    __shared__ __align__(16) unsigned short Bs[BN * BK];   // 8KB
    __shared__ float red[2][BN][3];                        // 3KB

    const int tid  = threadIdx.x;
    const int lane = tid & 63;
    const int w    = tid >> 6;
    const int wr   = w >> 1, wc = w & 1;
    const int quad = lane >> 4, ml = lane & 15;
    const int qtile = blockIdx.x;      // 0..31
    const int sp    = blockIdx.y;      // 0..NSPLIT-1
    const int m0    = qtile * BN;

    // staging mapping: wave w covers rows [w*32, w*32+32) in 2 passes of 16
    const int srow0 = w * 32 + (lane >> 2);
    const int srow1 = srow0 + 16;
    const int schunk = lane & 3;
    const unsigned short* qbase0 = qb + (size_t)(m0 + srow0) * KAUG + schunk * 8;
    const unsigned short* qbase1 = qb + (size_t)(m0 + srow1) * KAUG + schunk * 8;
    unsigned short* asb0 = As + (w * 32) * 32;
    unsigned short* asb1 = As + (w * 32 + 16) * 32;
    unsigned short* bsb0 = Bs + (w * 32) * 32;
    unsigned short* bsb1 = Bs + (w * 32 + 16) * 32;

    // fragment LDS offsets (constant): row*32 + (quad ^ (row&3))*8
    const int xorq = (quad ^ (ml & 3)) * 8;
    int aoff[4], boff[4];
    #pragma unroll
    for (int i = 0; i < 4; ++i) aoff[i] = (wr * 64 + i * 16 + ml) * 32 + xorq;
    #pragma unroll
    for (int j = 0; j < 4; ++j) boff[j] = (wc * 64 + j * 16 + ml) * 32 + xorq;

    float t0[4], t1[4], t2[4];
    #pragma unroll
    for (int j = 0; j < 4; ++j) { t0[j] = INFINITY; t1[j] = INFINITY; t2[j] = INFINITY; }

    for (int tile = sp; tile < NT2; tile += NSPLIT) {
        const int n0 = tile * BM;
        const unsigned short* dbase0 = dbb + (size_t)(n0 + srow0) * KAUG + schunk * 8;
        const unsigned short* dbase1 = dbb + (size_t)(n0 + srow1) * KAUG + schunk * 8;

        f32x4 acc[4][4];
        #pragma unroll
        for (int i = 0; i < 4; ++i)
            #pragma unroll
            for (int j = 0; j < 4; ++j) acc[i][j] = (f32x4){0.f, 0.f, 0.f, 0.f};

        for (int g = 0; g < KSTEPS; ++g) {
            __syncthreads();
            gl_lds16(dbase0 + g * 32, asb0);
            gl_lds16(dbase1 + g * 32, asb1);
            gl_lds16(qbase0 + g * 32, bsb0);
            gl_lds16(qbase1 + g * 32, bsb1);
            __syncthreads();

            bf16x8 af[4], bf[4];
            #pragma unroll
            for (int i = 0; i < 4; ++i) af[i] = *(const bf16x8*)(As + aoff[i]);
            #pragma unroll
            for (int j = 0; j < 4; ++j) bf[j] = *(const bf16x8*)(Bs + boff[j]);
            #pragma unroll
            for (int i = 0; i < 4; ++i)
                #pragma unroll
                for (int j = 0; j < 4; ++j)
                    acc[i][j] = __builtin_amdgcn_mfma_f32_16x16x32_bf16(af[i], bf[j], acc[i][j], 0, 0, 0);
        }

        // fused top-3 insert (acc already = x2 - 2 q.x via augmented K)
        #pragma unroll
        for (int j = 0; j < 4; ++j)
            #pragma unroll
            for (int i = 0; i < 4; ++i)
                #pragma unroll
                for (int r = 0; r < 4; ++r)
                    insert3(t0[j], t1[j], t2[j], acc[i][j][r]);
    }

    // cross-quad merge within wave (cols are per lane&15; quads hold disjoint rows)
    #pragma unroll
    for (int j = 0; j < 4; ++j) {
        #pragma unroll
        for (int mask = 16; mask <= 32; mask <<= 1) {
            float o0 = __shfl_xor(t0[j], mask);
            float o1 = __shfl_xor(t1[j], mask);
            float o2 = __shfl_xor(t2[j], mask);
            insert3(t0[j], t1[j], t2[j], o0);
            insert3(t0[j], t1[j], t2[j], o1);
            insert3(t0[j], t1[j], t2[j], o2);
        }
    }
    if (quad == 0) {
        #pragma unroll
        for (int j = 0; j < 4; ++j) {
            int col = wc * 64 + j * 16 + ml;
            red[wr][col][0] = t0[j];
            red[wr][col][1] = t1[j];
            red[wr][col][2] = t2[j];
        }
    }
    __syncthreads();
    if (tid < BN) {
        float a0 = red[0][tid][0], a1 = red[0][tid][1], a2 = red[0][tid][2];
        insert3(a0, a1, a2, red[1][tid][0]);
        insert3(a0, a1, a2, red[1][tid][1]);
        insert3(a0, a1, a2, red[1][tid][2]);
        float* dst = partials + ((size_t)(m0 + tid) * NSPLIT + sp) * 3;
        dst[0] = a0; dst[1] = a1; dst[2] = a2;
    }
}

// ---------------------------------------------------------------------------
// 5) merge partials, add q2, sqrt, mean
__global__ __launch_bounds__(256) void merge_ood(const float* __restrict__ partials,
                                                 const float* __restrict__ q2,
                                                 float* __restrict__ ood) {
    int m = blockIdx.x * 256 + threadIdx.x;
    if (m >= M) return;
    const float* pp = partials + (size_t)m * NSPLIT * 3;
    float a0 = INFINITY, a1 = INFINITY, a2 = INFINITY;
    #pragma unroll
    for (int j = 0; j < NSPLIT * 3; ++j) insert3(a0, a1, a2, pp[j]);
    float q = q2[m];
    float d0 = sqrtf(fmaxf(q + a0, 1e-12f));
    float d1 = sqrtf(fmaxf(q + a1, 1e-12f));
    float d2 = sqrtf(fmaxf(q + a2, 1e-12f));
    ood[m] = (d0 + d1 + d2) * (1.f / 3.f);
}

// ---------------------------------------------------------------------------
// 6) half-pixel bilinear 32x32 -> 512x512
__global__ __launch_bounds__(256) void upsample(const float* __restrict__ ood,
                                                float* __restrict__ out) {
    int idx = blockIdx.x * 256 + threadIdx.x;
    int ox = idx & (OUTW - 1);
    int oy = (idx >> 9) & (OUTH - 1);
    int bb = idx >> 18;
    float sx = (ox + 0.5f) * (32.f / OUTW) - 0.5f;
    float sy = (oy + 0.5f) * (32.f / OUTH) - 0.5f;
    float fx = floorf(sx), fy = floorf(sy);
    float wx = sx - fx, wy = sy - fy;
    int x0 = max(0, min(31, (int)fx));
    int x1 = max(0, min(31, (int)fx + 1));
    int y0 = max(0, min(31, (int)fy));
    int y1 = max(0, min(31, (int)fy + 1));
    const float* src = ood + bb * 1024;
    float v00 = src[y0 * 32 + x0];
    float v01 = src[y0 * 32 + x1];
    float v10 = src[y1 * 32 + x0];
    float v11 = src[y1 * 32 + x1];
    float top = v00 + wx * (v01 - v00);
    float bot = v10 + wx * (v11 - v10);
    out[idx] = top + wy * (bot - top);
}

// ---------------------------------------------------------------------------
extern "C" void kernel_launch(void* const* d_in, const int* in_sizes, int n_in,
                              void* d_out, int out_size, void* d_ws, size_t ws_size,
                              hipStream_t stream) {
    const float* emb = (const float*)d_in[0];
    const float* db  = (const float*)d_in[1];
    float* out = (float*)d_out;

    // workspace layout (bytes)
    char* ws = (char*)d_ws;
    unsigned short* dbb = (unsigned short*)ws;                       // 32,153,600 B
    unsigned short* qb  = (unsigned short*)(ws + 32153600);          //  6,553,600 B
    float* q2       = (float*)(ws + 38707200);                       //     16,384 B
    float* ood      = (float*)(ws + 38723584);                       //     16,384 B
    float* partials = (float*)(ws + 38739968);                       //  1,179,648 B

    db_convert<<<NDBP / 4, 256, 0, stream>>>(db, dbb);
    q_transpose<<<dim3(16, 12, 4), 256, 0, stream>>>(emb, qb);
    q_aug<<<64, 256, 0, stream>>>(qb);
    q_norms<<<M / 64, 256, 0, stream>>>(emb, q2);
    gemm_topk<<<dim3(M / BN, NSPLIT), 256, 0, stream>>>(dbb, qb, partials);
    merge_ood<<<(M + 255) / 256, 256, 0, stream>>>(partials, q2, ood);
    upsample<<<(B * OUTH * OUTW) / 256, 256, 0, stream>>>(ood, out);
}

// Round 3
// 311.496 us; speedup vs baseline: 7.4270x; 1.1439x over previous
//
#include <hip/hip_runtime.h>
#include <hip/hip_bf16.h>
#include <math.h>

// Problem constants
constexpr int B    = 4;
constexpr int D    = 768;
constexpr int HW   = 1024;
constexpr int M    = B * HW;        // 4096 queries
constexpr int NDB  = 20000;
constexpr int OUTH = 512;
constexpr int OUTW = 512;

constexpr int KAUG   = 800;         // 768 + aug chunk (x2 hi/lo, 1,1) + zero pad
constexpr int NCHUNK = KAUG / 8;    // 100 chunks of 8 bf16
constexpr int BM     = 128;         // db rows per tile
constexpr int BN     = 128;         // queries per tile
constexpr int KSTEPS = NCHUNK / 4;  // 25 (BK=32 = 4 chunks)
constexpr int NSPLIT = 32;
constexpr int NT2    = 157;         // ceil(20000/128)

typedef __bf16 bf16x8 __attribute__((ext_vector_type(8)));
typedef float  f32x4  __attribute__((ext_vector_type(4)));

__device__ __forceinline__ unsigned short f2bf(float x) {
    union { __hip_bfloat16 h; unsigned short s; } c;
    c.h = __float2bfloat16(x);
    return c.s;
}
__device__ __forceinline__ float bf2f(unsigned short u) {
    union { unsigned short s[2]; float f; } c;
    c.s[0] = 0; c.s[1] = u;
    return c.f;
}

__device__ __forceinline__ void insert3(float& t0, float& t1, float& t2, float d) {
    float a0 = fminf(d, t0);
    float b0 = fmaxf(d, t0);
    float a1 = fminf(b0, t1);
    float b1 = fmaxf(b0, t1);
    t0 = a0; t1 = a1;
    t2 = fminf(b1, t2);
}

union P8 { unsigned short u[8]; uint4 v; };

__device__ __forceinline__ void gl_lds16(const unsigned short* g, unsigned short* l) {
    __builtin_amdgcn_global_load_lds(
        (const __attribute__((address_space(1))) void*)g,
        (__attribute__((address_space(3))) void*)l, 16, 0, 0);
}

// ---------------------------------------------------------------------------
// 1) db [20000][768] fp32 -> dbt [157 tiles][100 chunks][128 rows][8] bf16.
//    Chunk 96 = (x2_hi, x2_lo, 0...); 97..99 zero; pad rows x2 = 1e30.
//    One block per tile; LDS fp32 panel transpose; fully coalesced.
__global__ __launch_bounds__(256) void db_convert(const float* __restrict__ db,
                                                  unsigned short* __restrict__ dbt) {
    __shared__ float panel[128][68];     // 64 cols + pad
    __shared__ float x2red[128][2];
    const int tile = blockIdx.x;
    const int t = threadIdx.x;
    const int n0 = tile * BM;
    const int rrow = t & 127, rhalf = t >> 7;
    float x2acc = 0.f;

    for (int kp = 0; kp < 12; ++kp) {
        const int k0 = kp * 64;
        __syncthreads();
        #pragma unroll
        for (int pass = 0; pass < 8; ++pass) {
            int idx = pass * 256 + t;          // 0..2047
            int row = idx >> 4, c4 = idx & 15;
            int n = n0 + row;
            float4 v = make_float4(0.f, 0.f, 0.f, 0.f);
            if (n < NDB) v = *(const float4*)(db + (size_t)n * D + k0 + c4 * 4);
            *(float4*)(&panel[row][c4 * 4]) = v;
        }
        __syncthreads();
        #pragma unroll
        for (int pass = 0; pass < 4; ++pass) {
            int idx = pass * 256 + t;          // 0..1023
            int ch = idx >> 7;                 // 0..7  (= pass*2 + rhalf)
            int row = idx & 127;               // == rrow
            P8 pk;
            #pragma unroll
            for (int j = 0; j < 8; ++j) {
                float v = panel[row][ch * 8 + j];
                pk.u[j] = f2bf(v);
                x2acc = fmaf(v, v, x2acc);
            }
            *(uint4*)(dbt + (((size_t)tile * NCHUNK + kp * 8 + ch) * BM + row) * 8) = pk.v;
        }
    }
    x2red[rrow][rhalf] = x2acc;
    __syncthreads();
    #pragma unroll
    for (int pass = 0; pass < 2; ++pass) {
        int idx = pass * 256 + t;              // 0..511
        int ch = 96 + (idx >> 7), row = idx & 127;
        P8 pk; pk.v = make_uint4(0, 0, 0, 0);
        if (ch == 96) {
            float s = x2red[row][0] + x2red[row][1];
            if (n0 + row >= NDB) s = 1e30f;
            unsigned short hi = f2bf(s);
            pk.u[0] = hi;
            pk.u[1] = f2bf(s - bf2f(hi));
        }
        *(uint4*)(dbt + (((size_t)tile * NCHUNK + ch) * BM + row) * 8) = pk.v;
    }
}

// ---------------------------------------------------------------------------
// 2) emb [4][768][1024] -> qbt [32 qtiles][100 chunks][128 rows][8] bf16,
//    scaled by -2. Aug chunk 96 = (1,1,0...). Block = (qtile, 64-d panel).
__global__ __launch_bounds__(256) void q_convert(const float* __restrict__ emb,
                                                 unsigned short* __restrict__ qbt) {
    __shared__ float panel[64][132];     // 128 cols + pad
    const int qt = blockIdx.x;           // 0..31
    const int kp = blockIdx.y;           // 0..11
    const int t = threadIdx.x;
    const int b = qt >> 3;
    const int p0 = (qt & 7) * 128;
    const int k0 = kp * 64;

    #pragma unroll
    for (int pass = 0; pass < 8; ++pass) {
        int idx = pass * 256 + t;          // 0..2047
        int d = idx >> 5, p4 = idx & 31;
        float4 v = *(const float4*)(emb + ((size_t)b * D + k0 + d) * HW + p0 + p4 * 4);
        *(float4*)(&panel[d][p4 * 4]) = v;
    }
    __syncthreads();
    #pragma unroll
    for (int pass = 0; pass < 4; ++pass) {
        int idx = pass * 256 + t;          // 0..1023
        int ch = idx >> 7, row = idx & 127;
        P8 pk;
        #pragma unroll
        for (int j = 0; j < 8; ++j) pk.u[j] = f2bf(-2.f * panel[ch * 8 + j][row]);
        *(uint4*)(qbt + (((size_t)qt * NCHUNK + kp * 8 + ch) * BN + row) * 8) = pk.v;
    }
    if (kp == 11) {
        #pragma unroll
        for (int pass = 0; pass < 2; ++pass) {
            int idx = pass * 256 + t;
            int ch = 96 + (idx >> 7), row = idx & 127;
            P8 pk; pk.v = make_uint4(0, 0, 0, 0);
            if (ch == 96) { pk.u[0] = f2bf(1.f); pk.u[1] = f2bf(1.f); }
            *(uint4*)(qbt + (((size_t)qt * NCHUNK + ch) * BN + row) * 8) = pk.v;
        }
    }
}

// ---------------------------------------------------------------------------
// 3) query squared norms (fp32 exact)
__global__ __launch_bounds__(256) void q_norms(const float* __restrict__ emb,
                                               float* __restrict__ q2) {
    __shared__ float red[4][64];
    int t = threadIdx.x;
    int p = t & 63;
    int dg = t >> 6;
    int m0 = blockIdx.x * 64;
    int m = m0 + p;
    int b = m >> 10;
    int pp = m & 1023;
    const float* base = emb + (size_t)b * D * HW + pp;
    float s = 0.f;
    #pragma unroll 8
    for (int d = dg * 192; d < dg * 192 + 192; ++d) {
        float v = base[(size_t)d * HW];
        s = fmaf(v, v, s);
    }
    red[dg][p] = s;
    __syncthreads();
    if (t < 64) q2[m0 + t] = red[0][t] + red[1][t] + red[2][t] + red[3][t];
}

// ---------------------------------------------------------------------------
// 4) MFMA GEMM + fused running top-3. score[n][m] = x2[n] - 2 db[n].q[m]
//    via augmented K. Tiled operands -> conflict-free LDS, trivial staging.
//    XCD-affinity: all 32 qtiles of a split co-locate on one XCD (bid%8).
__global__ __launch_bounds__(256, 4) void gemm_topk(const unsigned short* __restrict__ dbt,
                                                    const unsigned short* __restrict__ qbt,
                                                    float* __restrict__ partials) {
    __shared__ __align__(16) unsigned short As[4 * BM * 8];   // 8 KB  [slot][row][8]
    __shared__ __align__(16) unsigned short Bs[4 * BN * 8];   // 8 KB
    __shared__ float red[2][BN][3];                           // 3 KB

    const int tid  = threadIdx.x;
    const int lane = tid & 63;
    const int w    = tid >> 6;
    const int wr   = w >> 1, wc = w & 1;
    const int quad = lane >> 4, ml = lane & 15;

    const int bid   = blockIdx.x;           // 0..1023
    const int xcd   = bid & 7;
    const int j     = bid >> 3;             // 0..127
    const int sp    = xcd + 8 * (j >> 5);   // split 0..31
    const int qtile = j & 31;
    const int m0    = qtile * BN;

    // fragment LDS element offsets (shorts)
    int aoff[4], boff[4];
    #pragma unroll
    for (int i = 0; i < 4; ++i) aoff[i] = (quad * BM + wr * 64 + i * 16 + ml) * 8;
    #pragma unroll
    for (int jj = 0; jj < 4; ++jj) boff[jj] = (quad * BN + wc * 64 + jj * 16 + ml) * 8;

    unsigned short* asl0 = As + w * 1024;
    unsigned short* bsl0 = Bs + w * 1024;
    const unsigned short* qbase = qbt + (((size_t)qtile * NCHUNK + w) * BN + lane) * 8;

    float t0[4], t1[4], t2[4];
    #pragma unroll
    for (int jj = 0; jj < 4; ++jj) { t0[jj] = INFINITY; t1[jj] = INFINITY; t2[jj] = INFINITY; }

    for (int tile = sp; tile < NT2; tile += NSPLIT) {
        const unsigned short* aptr = dbt + (((size_t)tile * NCHUNK + w) * BM + lane) * 8;
        const unsigned short* qptr = qbase;

        f32x4 acc[4][4];
        #pragma unroll
        for (int i = 0; i < 4; ++i)
            #pragma unroll
            for (int jj = 0; jj < 4; ++jj) acc[i][jj] = (f32x4){0.f, 0.f, 0.f, 0.f};

        for (int g = 0; g < KSTEPS; ++g) {
            __syncthreads();
            gl_lds16(aptr,       asl0);
            gl_lds16(aptr + 512, asl0 + 512);
            gl_lds16(qptr,       bsl0);
            gl_lds16(qptr + 512, bsl0 + 512);
            aptr += 4096;   // 4 chunks * 128 rows * 8
            qptr += 4096;
            __syncthreads();

            bf16x8 af[4], bfr[4];
            #pragma unroll
            for (int i = 0; i < 4; ++i) af[i] = *(const bf16x8*)(As + aoff[i]);
            #pragma unroll
            for (int jj = 0; jj < 4; ++jj) bfr[jj] = *(const bf16x8*)(Bs + boff[jj]);
            #pragma unroll
            for (int i = 0; i < 4; ++i)
                #pragma unroll
                for (int jj = 0; jj < 4; ++jj)
                    acc[i][jj] = __builtin_amdgcn_mfma_f32_16x16x32_bf16(af[i], bfr[jj], acc[i][jj], 0, 0, 0);
        }

        // fused top-3 insert (acc = x2 - 2 q.x via augmented K)
        #pragma unroll
        for (int jj = 0; jj < 4; ++jj)
            #pragma unroll
            for (int i = 0; i < 4; ++i)
                #pragma unroll
                for (int r = 0; r < 4; ++r)
                    insert3(t0[jj], t1[jj], t2[jj], acc[i][jj][r]);
    }

    // cross-quad merge within wave (cols per lane&15; quads hold disjoint rows)
    #pragma unroll
    for (int jj = 0; jj < 4; ++jj) {
        #pragma unroll
        for (int mask = 16; mask <= 32; mask <<= 1) {
            float o0 = __shfl_xor(t0[jj], mask);
            float o1 = __shfl_xor(t1[jj], mask);
            float o2 = __shfl_xor(t2[jj], mask);
            insert3(t0[jj], t1[jj], t2[jj], o0);
            insert3(t0[jj], t1[jj], t2[jj], o1);
            insert3(t0[jj], t1[jj], t2[jj], o2);
        }
    }
    if (quad == 0) {
        #pragma unroll
        for (int jj = 0; jj < 4; ++jj) {
            int col = wc * 64 + jj * 16 + ml;
            red[wr][col][0] = t0[jj];
            red[wr][col][1] = t1[jj];
            red[wr][col][2] = t2[jj];
        }
    }
    __syncthreads();
    if (tid < BN) {
        float a0 = red[0][tid][0], a1 = red[0][tid][1], a2 = red[0][tid][2];
        insert3(a0, a1, a2, red[1][tid][0]);
        insert3(a0, a1, a2, red[1][tid][1]);
        insert3(a0, a1, a2, red[1][tid][2]);
        float* dst = partials + ((size_t)(m0 + tid) * NSPLIT + sp) * 3;
        dst[0] = a0; dst[1] = a1; dst[2] = a2;
    }
}

// ---------------------------------------------------------------------------
// 5) merge partials, add q2, sqrt, mean
__global__ __launch_bounds__(256) void merge_ood(const float* __restrict__ partials,
                                                 const float* __restrict__ q2,
                                                 float* __restrict__ ood) {
    int m = blockIdx.x * 256 + threadIdx.x;
    if (m >= M) return;
    const float* pp = partials + (size_t)m * NSPLIT * 3;
    float a0 = INFINITY, a1 = INFINITY, a2 = INFINITY;
    #pragma unroll
    for (int j = 0; j < NSPLIT * 3; ++j) insert3(a0, a1, a2, pp[j]);
    float q = q2[m];
    float d0 = sqrtf(fmaxf(q + a0, 1e-12f));
    float d1 = sqrtf(fmaxf(q + a1, 1e-12f));
    float d2 = sqrtf(fmaxf(q + a2, 1e-12f));
    ood[m] = (d0 + d1 + d2) * (1.f / 3.f);
}

// ---------------------------------------------------------------------------
// 6) half-pixel bilinear 32x32 -> 512x512
__global__ __launch_bounds__(256) void upsample(const float* __restrict__ ood,
                                                float* __restrict__ out) {
    int idx = blockIdx.x * 256 + threadIdx.x;
    int ox = idx & (OUTW - 1);
    int oy = (idx >> 9) & (OUTH - 1);
    int bb = idx >> 18;
    float sx = (ox + 0.5f) * (32.f / OUTW) - 0.5f;
    float sy = (oy + 0.5f) * (32.f / OUTH) - 0.5f;
    float fx = floorf(sx), fy = floorf(sy);
    float wx = sx - fx, wy = sy - fy;
    int x0 = max(0, min(31, (int)fx));
    int x1 = max(0, min(31, (int)fx + 1));
    int y0 = max(0, min(31, (int)fy));
    int y1 = max(0, min(31, (int)fy + 1));
    const float* src = ood + bb * 1024;
    float v00 = src[y0 * 32 + x0];
    float v01 = src[y0 * 32 + x1];
    float v10 = src[y1 * 32 + x0];
    float v11 = src[y1 * 32 + x1];
    float top = v00 + wx * (v01 - v00);
    float bot = v10 + wx * (v11 - v10);
    out[idx] = top + wy * (bot - top);
}

// ---------------------------------------------------------------------------
extern "C" void kernel_launch(void* const* d_in, const int* in_sizes, int n_in,
                              void* d_out, int out_size, void* d_ws, size_t ws_size,
                              hipStream_t stream) {
    const float* emb = (const float*)d_in[0];
    const float* db  = (const float*)d_in[1];
    float* out = (float*)d_out;

    // workspace layout (bytes), total ~40.3 MB
    char* ws = (char*)d_ws;
    unsigned short* dbt = (unsigned short*)ws;                  // 157*100*128*8*2 = 32,153,600
    unsigned short* qbt = (unsigned short*)(ws + 32153600);     // 32*100*128*8*2  =  6,553,600
    float* q2       = (float*)(ws + 38707200);                  // 16,384
    float* ood      = (float*)(ws + 38723584);                  // 16,384
    float* partials = (float*)(ws + 38739968);                  // 4096*32*3*4 = 1,572,864

    db_convert<<<NT2, 256, 0, stream>>>(db, dbt);
    q_convert<<<dim3(32, 12), 256, 0, stream>>>(emb, qbt);
    q_norms<<<M / 64, 256, 0, stream>>>(emb, q2);
    gemm_topk<<<NSPLIT * 32, 256, 0, stream>>>(dbt, qbt, partials);
    merge_ood<<<(M + 255) / 256, 256, 0, stream>>>(partials, q2, ood);
    upsample<<<(B * OUTH * OUTW) / 256, 256, 0, stream>>>(ood, out);
}

// Round 4
// 234.380 us; speedup vs baseline: 9.8706x; 1.3290x over previous
//
#include <hip/hip_runtime.h>
#include <hip/hip_bf16.h>
#include <math.h>

// Problem constants
constexpr int B    = 4;
constexpr int D    = 768;
constexpr int HW   = 1024;
constexpr int M    = B * HW;        // 4096 queries
constexpr int NDB  = 20000;
constexpr int NDBP = 20096;         // 157*128
constexpr int OUTH = 512;
constexpr int OUTW = 512;

constexpr int BM     = 128;         // db rows per tile
constexpr int BN     = 128;         // queries per tile
constexpr int BK     = 64;          // K per step (fp8, 32x32x64)
constexpr int KSTEPS = D / BK;      // 12
constexpr int NSPLIT = 32;
constexpr int NT2    = 157;
constexpr int STEPB  = BM * BK;     // 8192 bytes per operand step-block

typedef int   i32x8  __attribute__((ext_vector_type(8)));
typedef float f32x16 __attribute__((ext_vector_type(16)));

__device__ __forceinline__ void insert3(float& t0, float& t1, float& t2, float d) {
    float a0 = fminf(d, t0);
    float b0 = fmaxf(d, t0);
    float a1 = fminf(b0, t1);
    float b1 = fmaxf(b0, t1);
    t0 = a0; t1 = a1;
    t2 = fminf(b1, t2);
}

__device__ __forceinline__ unsigned int pack4_fp8(float a, float b, float c, float d) {
    int v = __builtin_amdgcn_cvt_pk_fp8_f32(a, b, 0, false);
    v = __builtin_amdgcn_cvt_pk_fp8_f32(c, d, v, true);
    return (unsigned int)v;
}

__device__ __forceinline__ void gl_lds16(const unsigned char* g, unsigned char* l) {
    __builtin_amdgcn_global_load_lds(
        (const __attribute__((address_space(1))) void*)g,
        (__attribute__((address_space(3))) void*)l, 16, 0, 0);
}

// ---------------------------------------------------------------------------
// 1) db [20000][768] fp32 -> fp8 tiled [157][12 steps][rg 4][h2 2][kc 2][r 32][16B]
//    One block per (tile, step): fully parallel (1884 blocks).
__global__ __launch_bounds__(256) void db_convert(const float* __restrict__ db,
                                                  uint4* __restrict__ dbt8) {
    __shared__ float panel[128][68];
    const int tile = blockIdx.x;
    const int g    = blockIdx.y;
    const int t    = threadIdx.x;
    const int n0   = tile * BM;
    const int k0   = g * BK;

    #pragma unroll
    for (int pass = 0; pass < 8; ++pass) {
        int idx = pass * 256 + t;            // 0..2047
        int row = idx >> 4, c4 = idx & 15;
        int n = n0 + row;
        float4 v = make_float4(0.f, 0.f, 0.f, 0.f);
        if (n < NDB) v = *(const float4*)(db + (size_t)n * D + k0 + c4 * 4);
        *(float4*)(&panel[row][c4 * 4]) = v;
    }
    __syncthreads();
    #pragma unroll
    for (int pass = 0; pass < 2; ++pass) {
        int idx = pass * 256 + t;            // 0..511  bits [rg:2][h2:1][kc:1][r:5]
        int r  = idx & 31;
        int kc = (idx >> 5) & 1;
        int h2 = (idx >> 6) & 1;
        int rg = idx >> 7;
        int row  = rg * 32 + r;
        int kloc = kc * 32 + h2 * 16;
        const float* src = &panel[row][kloc];
        uint4 o;
        o.x = pack4_fp8(src[0],  src[1],  src[2],  src[3]);
        o.y = pack4_fp8(src[4],  src[5],  src[6],  src[7]);
        o.z = pack4_fp8(src[8],  src[9],  src[10], src[11]);
        o.w = pack4_fp8(src[12], src[13], src[14], src[15]);
        dbt8[((size_t)tile * KSTEPS + g) * 512 + idx] = o;
    }
}

// ---------------------------------------------------------------------------
// 2) db row squared norms (fp32 exact); pad rows -> 1e30
__global__ __launch_bounds__(256) void db_x2(const float* __restrict__ db,
                                             float* __restrict__ x2) {
    int wave = threadIdx.x >> 6;
    int lane = threadIdx.x & 63;
    int n = blockIdx.x * 4 + wave;
    if (n >= NDBP) return;
    if (n >= NDB) { if (lane == 0) x2[n] = 1e30f; return; }
    const float4* row = (const float4*)(db + (size_t)n * D);   // 192 float4
    float s = 0.f;
    #pragma unroll
    for (int j = 0; j < 3; ++j) {
        float4 v = row[lane + j * 64];
        s += v.x * v.x + v.y * v.y + v.z * v.z + v.w * v.w;
    }
    #pragma unroll
    for (int m = 1; m < 64; m <<= 1) s += __shfl_xor(s, m);
    if (lane == 0) x2[n] = s;
}

// ---------------------------------------------------------------------------
// 3) emb [4][768][1024] -> fp8 (-2*q) tiled [32 qtiles][12][rg][h2][kc][r][16B]
__global__ __launch_bounds__(256) void q_convert(const float* __restrict__ emb,
                                                 uint4* __restrict__ qbt8) {
    __shared__ float panel[64][132];     // [k][p]
    const int qt = blockIdx.x;           // 0..31
    const int g  = blockIdx.y;           // 0..11
    const int t  = threadIdx.x;
    const int b  = qt >> 3;
    const int p0 = (qt & 7) * 128;
    const int k0 = g * BK;

    #pragma unroll
    for (int pass = 0; pass < 8; ++pass) {
        int idx = pass * 256 + t;          // 0..2047
        int d = idx >> 5, p4 = idx & 31;
        float4 v = *(const float4*)(emb + ((size_t)b * D + k0 + d) * HW + p0 + p4 * 4);
        *(float4*)(&panel[d][p4 * 4]) = v;
    }
    __syncthreads();
    #pragma unroll
    for (int pass = 0; pass < 2; ++pass) {
        int idx = pass * 256 + t;          // bits [rg:2][h2:1][kc:1][r:5]
        int r  = idx & 31;
        int kc = (idx >> 5) & 1;
        int h2 = (idx >> 6) & 1;
        int rg = idx >> 7;
        int prow = rg * 32 + r;
        int kloc = kc * 32 + h2 * 16;
        float v[16];
        #pragma unroll
        for (int j = 0; j < 16; ++j) v[j] = -2.f * panel[kloc + j][prow];
        uint4 o;
        o.x = pack4_fp8(v[0],  v[1],  v[2],  v[3]);
        o.y = pack4_fp8(v[4],  v[5],  v[6],  v[7]);
        o.z = pack4_fp8(v[8],  v[9],  v[10], v[11]);
        o.w = pack4_fp8(v[12], v[13], v[14], v[15]);
        qbt8[((size_t)qt * KSTEPS + g) * 512 + idx] = o;
    }
}

// ---------------------------------------------------------------------------
// 4) query squared norms (fp32 exact)
__global__ __launch_bounds__(256) void q_norms(const float* __restrict__ emb,
                                               float* __restrict__ q2) {
    __shared__ float red[4][64];
    int t = threadIdx.x;
    int p = t & 63;
    int dg = t >> 6;
    int m0 = blockIdx.x * 64;
    int m = m0 + p;
    int b = m >> 10;
    int pp = m & 1023;
    const float* base = emb + (size_t)b * D * HW + pp;
    float s = 0.f;
    #pragma unroll 8
    for (int d = dg * 192; d < dg * 192 + 192; ++d) {
        float v = base[(size_t)d * HW];
        s = fmaf(v, v, s);
    }
    red[dg][p] = s;
    __syncthreads();
    if (t < 64) q2[m0 + t] = red[0][t] + red[1][t] + red[2][t] + red[3][t];
}

// ---------------------------------------------------------------------------
// 5) MX-fp8 MFMA GEMM (scale=1.0) + fp32 x2 epilogue + fused top-3.
//    score[n][m] = x2[n] - 2 db[n].q[m]  (the -2 folded into q conversion)
__global__ __launch_bounds__(256, 4) void gemm_topk(const unsigned char* __restrict__ dbt8,
                                                    const unsigned char* __restrict__ qbt8,
                                                    const float* __restrict__ x2g,
                                                    float* __restrict__ partials) {
    __shared__ __align__(16) unsigned char As[STEPB];   // 8 KB
    __shared__ __align__(16) unsigned char Bs[STEPB];   // 8 KB
    __shared__ float X2s[BM];                           // 512 B
    __shared__ float red[2][BN][3];                     // 3 KB

    const int tid  = threadIdx.x;
    const int lane = tid & 63;
    const int w    = tid >> 6;
    const int wr   = w >> 1, wc = w & 1;
    const int h    = lane >> 5;          // k-chunk / row-half selector
    const int l31  = lane & 31;

    const int bid   = blockIdx.x;        // 0..1023
    const int xcd   = bid & 7;
    const int j     = bid >> 3;
    const int sp    = xcd + 8 * (j >> 5);
    const int qtile = j & 31;
    const int m0    = qtile * BN;

    // fragment LDS byte offsets: addr = rg*2048 + h2*1024 + kc*512 + r*16
    // lane: kc = h, r = l31  ->  canonical base + lane*16 per (rg,h2): conflict-free
    const int afrag = (wr * 2) * 2048 + h * 512 + l31 * 16;   // + i*2048 + h2*1024
    const int bfrag = (wc * 2) * 2048 + h * 512 + l31 * 16;

    const int lb = lane * 16;
    const unsigned char* qstep = qbt8 + (size_t)qtile * KSTEPS * STEPB + w * 2048 + lb;

    float t0[2], t1[2], t2[2];
    #pragma unroll
    for (int jj = 0; jj < 2; ++jj) { t0[jj] = INFINITY; t1[jj] = INFINITY; t2[jj] = INFINITY; }

    for (int tile = sp; tile < NT2; tile += NSPLIT) {
        const int n0 = tile * BM;
        const unsigned char* astep = dbt8 + (size_t)tile * KSTEPS * STEPB + w * 2048 + lb;
        const unsigned char* bstep = qstep;

        f32x16 acc[2][2];
        #pragma unroll
        for (int i = 0; i < 2; ++i)
            #pragma unroll
            for (int jj = 0; jj < 2; ++jj)
                #pragma unroll
                for (int r = 0; r < 16; ++r) acc[i][jj][r] = 0.f;

        for (int g = 0; g < KSTEPS; ++g) {
            __syncthreads();
            gl_lds16(astep,        As + w * 2048);
            gl_lds16(astep + 1024, As + w * 2048 + 1024);
            gl_lds16(bstep,        Bs + w * 2048);
            gl_lds16(bstep + 1024, Bs + w * 2048 + 1024);
            if (g == 0 && tid < BM) X2s[tid] = x2g[n0 + tid];
            astep += STEPB;
            bstep += STEPB;
            __syncthreads();

            i32x8 af[2], bf[2];
            #pragma unroll
            for (int i = 0; i < 2; ++i) {
                int4 lo = *(const int4*)(As + afrag + i * 2048);
                int4 hi = *(const int4*)(As + afrag + i * 2048 + 1024);
                af[i] = (i32x8){lo.x, lo.y, lo.z, lo.w, hi.x, hi.y, hi.z, hi.w};
            }
            #pragma unroll
            for (int jj = 0; jj < 2; ++jj) {
                int4 lo = *(const int4*)(Bs + bfrag + jj * 2048);
                int4 hi = *(const int4*)(Bs + bfrag + jj * 2048 + 1024);
                bf[jj] = (i32x8){lo.x, lo.y, lo.z, lo.w, hi.x, hi.y, hi.z, hi.w};
            }
            #pragma unroll
            for (int i = 0; i < 2; ++i)
                #pragma unroll
                for (int jj = 0; jj < 2; ++jj)
                    acc[i][jj] = __builtin_amdgcn_mfma_scale_f32_32x32x64_f8f6f4(
                        af[i], bf[jj], acc[i][jj], 0, 0,
                        0, 0x7f7f7f7f, 0, 0x7f7f7f7f);
        }

        // epilogue: s = x2[row] + acc  (rows: wr*64 + i*32 + rg2*8 + 4h + rr)
        #pragma unroll
        for (int i = 0; i < 2; ++i) {
            #pragma unroll
            for (int rg2 = 0; rg2 < 4; ++rg2) {
                float4 xv = *(const float4*)&X2s[wr * 64 + i * 32 + rg2 * 8 + 4 * h];
                #pragma unroll
                for (int jj = 0; jj < 2; ++jj) {
                    #pragma unroll
                    for (int rr = 0; rr < 4; ++rr) {
                        float s = acc[i][jj][rg2 * 4 + rr] + ((const float*)&xv)[rr];
                        insert3(t0[jj], t1[jj], t2[jj], s);
                    }
                }
            }
        }
    }

    // merge across the two row-halves (lane ^ 32), then across wr via LDS
    #pragma unroll
    for (int jj = 0; jj < 2; ++jj) {
        float o0 = __shfl_xor(t0[jj], 32);
        float o1 = __shfl_xor(t1[jj], 32);
        float o2 = __shfl_xor(t2[jj], 32);
        insert3(t0[jj], t1[jj], t2[jj], o0);
        insert3(t0[jj], t1[jj], t2[jj], o1);
        insert3(t0[jj], t1[jj], t2[jj], o2);
    }
    if (h == 0) {
        #pragma unroll
        for (int jj = 0; jj < 2; ++jj) {
            int col = wc * 64 + jj * 32 + l31;
            red[wr][col][0] = t0[jj];
            red[wr][col][1] = t1[jj];
            red[wr][col][2] = t2[jj];
        }
    }
    __syncthreads();
    if (tid < BN) {
        float a0 = red[0][tid][0], a1 = red[0][tid][1], a2 = red[0][tid][2];
        insert3(a0, a1, a2, red[1][tid][0]);
        insert3(a0, a1, a2, red[1][tid][1]);
        insert3(a0, a1, a2, red[1][tid][2]);
        float* dst = partials + ((size_t)(m0 + tid) * NSPLIT + sp) * 3;
        dst[0] = a0; dst[1] = a1; dst[2] = a2;
    }
}

// ---------------------------------------------------------------------------
// 6) merge partials, add q2, sqrt, mean
__global__ __launch_bounds__(256) void merge_ood(const float* __restrict__ partials,
                                                 const float* __restrict__ q2,
                                                 float* __restrict__ ood) {
    int m = blockIdx.x * 256 + threadIdx.x;
    if (m >= M) return;
    const float* pp = partials + (size_t)m * NSPLIT * 3;
    float a0 = INFINITY, a1 = INFINITY, a2 = INFINITY;
    #pragma unroll
    for (int j = 0; j < NSPLIT * 3; ++j) insert3(a0, a1, a2, pp[j]);
    float q = q2[m];
    float d0 = sqrtf(fmaxf(q + a0, 1e-12f));
    float d1 = sqrtf(fmaxf(q + a1, 1e-12f));
    float d2 = sqrtf(fmaxf(q + a2, 1e-12f));
    ood[m] = (d0 + d1 + d2) * (1.f / 3.f);
}

// ---------------------------------------------------------------------------
// 7) half-pixel bilinear 32x32 -> 512x512
__global__ __launch_bounds__(256) void upsample(const float* __restrict__ ood,
                                                float* __restrict__ out) {
    int idx = blockIdx.x * 256 + threadIdx.x;
    int ox = idx & (OUTW - 1);
    int oy = (idx >> 9) & (OUTH - 1);
    int bb = idx >> 18;
    float sx = (ox + 0.5f) * (32.f / OUTW) - 0.5f;
    float sy = (oy + 0.5f) * (32.f / OUTH) - 0.5f;
    float fx = floorf(sx), fy = floorf(sy);
    float wx = sx - fx, wy = sy - fy;
    int x0 = max(0, min(31, (int)fx));
    int x1 = max(0, min(31, (int)fx + 1));
    int y0 = max(0, min(31, (int)fy));
    int y1 = max(0, min(31, (int)fy + 1));
    const float* src = ood + bb * 1024;
    float v00 = src[y0 * 32 + x0];
    float v01 = src[y0 * 32 + x1];
    float v10 = src[y1 * 32 + x0];
    float v11 = src[y1 * 32 + x1];
    float top = v00 + wx * (v01 - v00);
    float bot = v10 + wx * (v11 - v10);
    out[idx] = top + wy * (bot - top);
}

// ---------------------------------------------------------------------------
extern "C" void kernel_launch(void* const* d_in, const int* in_sizes, int n_in,
                              void* d_out, int out_size, void* d_ws, size_t ws_size,
                              hipStream_t stream) {
    const float* emb = (const float*)d_in[0];
    const float* db  = (const float*)d_in[1];
    float* out = (float*)d_out;

    // workspace layout (bytes), total ~20.3 MB
    char* ws = (char*)d_ws;
    unsigned char* dbt8 = (unsigned char*)ws;                    // 157*12*8192 = 15,433,728
    unsigned char* qbt8 = (unsigned char*)(ws + 15433728);       // 32*12*8192  =  3,145,728
    float* x2       = (float*)(ws + 18579456);                   // 20096*4 = 80,384
    float* q2       = (float*)(ws + 18659840);                   // 16,384
    float* ood      = (float*)(ws + 18676224);                   // 16,384
    float* partials = (float*)(ws + 18692608);                   // 4096*32*3*4 = 1,572,864

    db_convert<<<dim3(NT2, KSTEPS), 256, 0, stream>>>(db, (uint4*)dbt8);
    db_x2<<<NDBP / 4, 256, 0, stream>>>(db, x2);
    q_convert<<<dim3(32, KSTEPS), 256, 0, stream>>>(emb, (uint4*)qbt8);
    q_norms<<<M / 64, 256, 0, stream>>>(emb, q2);
    gemm_topk<<<NSPLIT * 32, 256, 0, stream>>>(dbt8, qbt8, x2, partials);
    merge_ood<<<(M + 255) / 256, 256, 0, stream>>>(partials, q2, ood);
    upsample<<<(B * OUTH * OUTW) / 256, 256, 0, stream>>>(ood, out);
}

// Round 5
// 213.614 us; speedup vs baseline: 10.8302x; 1.0972x over previous
//
#include <hip/hip_runtime.h>
#include <hip/hip_bf16.h>
#include <math.h>

// Problem constants
constexpr int B    = 4;
constexpr int D    = 768;
constexpr int HW   = 1024;
constexpr int M    = B * HW;        // 4096 queries
constexpr int NDB  = 20000;
constexpr int NDBP = 20096;         // 157*128
constexpr int OUTH = 512;
constexpr int OUTW = 512;

constexpr int BM     = 128;         // db rows per tile
constexpr int BN     = 128;         // queries per tile
constexpr int KSTEPS = D / 64;      // 12 (64-K step-blocks in the tiled layout)
constexpr int GSTEPS = KSTEPS / 2;  // 6 barrier-pairs per tile (BK=128)
constexpr int NSPLIT = 32;
constexpr int NT2    = 157;
constexpr int STEPB  = BM * 64;     // 8192 bytes per operand 64-K step-block

typedef int   i32x8  __attribute__((ext_vector_type(8)));
typedef float f32x16 __attribute__((ext_vector_type(16)));

__device__ __forceinline__ void insert3(float& t0, float& t1, float& t2, float d) {
    float a0 = fminf(d, t0);
    float b0 = fmaxf(d, t0);
    float a1 = fminf(b0, t1);
    float b1 = fmaxf(b0, t1);
    t0 = a0; t1 = a1;
    t2 = fminf(b1, t2);
}

__device__ __forceinline__ unsigned int pack4_fp8(float a, float b, float c, float d) {
    int v = __builtin_amdgcn_cvt_pk_fp8_f32(a, b, 0, false);
    v = __builtin_amdgcn_cvt_pk_fp8_f32(c, d, v, true);
    return (unsigned int)v;
}

__device__ __forceinline__ void gl_lds16(const unsigned char* g, unsigned char* l) {
    __builtin_amdgcn_global_load_lds(
        (const __attribute__((address_space(1))) void*)g,
        (__attribute__((address_space(3))) void*)l, 16, 0, 0);
}

// ---------------------------------------------------------------------------
// 1) db [20000][768] fp32 -> fp8 tiled [157][12][rg 4][h2 2][kc 2][r 32][16B]
//    Direct global reads (64 contiguous B per item), no LDS transpose.
//    Also emits per-(tile,g,row) x2 partial sums (exact fp32).
__global__ __launch_bounds__(256) void db_convert(const float* __restrict__ db,
                                                  uint4* __restrict__ dbt8,
                                                  float* __restrict__ x2p) {
    __shared__ float part[512];
    const int tile = blockIdx.x;
    const int g    = blockIdx.y;
    const int t    = threadIdx.x;
    const int n0   = tile * BM;

    #pragma unroll
    for (int pass = 0; pass < 2; ++pass) {
        int idx = pass * 256 + t;            // bits [rg:2][h2:1][kc:1][r:5]
        int r  = idx & 31;
        int kc = (idx >> 5) & 1;
        int h2 = (idx >> 6) & 1;
        int rg = idx >> 7;
        int row = rg * 32 + r;
        int n = n0 + row;
        int kb = g * 64 + kc * 32 + h2 * 16;
        float4 v0 = make_float4(0.f, 0.f, 0.f, 0.f), v1 = v0, v2 = v0, v3 = v0;
        if (n < NDB) {
            const float4* p = (const float4*)(db + (size_t)n * D + kb);
            v0 = p[0]; v1 = p[1]; v2 = p[2]; v3 = p[3];
        }
        float ss = v0.x*v0.x + v0.y*v0.y + v0.z*v0.z + v0.w*v0.w
                 + v1.x*v1.x + v1.y*v1.y + v1.z*v1.z + v1.w*v1.w
                 + v2.x*v2.x + v2.y*v2.y + v2.z*v2.z + v2.w*v2.w
                 + v3.x*v3.x + v3.y*v3.y + v3.z*v3.z + v3.w*v3.w;
        uint4 o;
        o.x = pack4_fp8(v0.x, v0.y, v0.z, v0.w);
        o.y = pack4_fp8(v1.x, v1.y, v1.z, v1.w);
        o.z = pack4_fp8(v2.x, v2.y, v2.z, v2.w);
        o.w = pack4_fp8(v3.x, v3.y, v3.z, v3.w);
        dbt8[((size_t)tile * KSTEPS + g) * 512 + idx] = o;
        part[idx] = ss;
    }
    __syncthreads();
    if (t < 128) {
        int rg = t >> 5, r = t & 31;
        int base = rg * 128 + r;
        float s = part[base] + part[base + 32] + part[base + 64] + part[base + 96];
        x2p[((size_t)tile * KSTEPS + g) * 128 + t] = s;
    }
}

// 1b) reduce 12 x2 partials -> x2[n]; pad rows get 1e30
__global__ __launch_bounds__(256) void x2_reduce(const float* __restrict__ x2p,
                                                 float* __restrict__ x2) {
    int n = blockIdx.x * 256 + threadIdx.x;
    if (n >= NDBP) return;
    if (n >= NDB) { x2[n] = 1e30f; return; }
    const float* p = x2p + (size_t)(n >> 7) * KSTEPS * 128 + (n & 127);
    float s = 0.f;
    #pragma unroll
    for (int g = 0; g < KSTEPS; ++g) s += p[g * 128];
    x2[n] = s;
}

// ---------------------------------------------------------------------------
// 2) emb [4][768][1024] -> fp8 (-2*q) tiled [32][12][rg][h2][kc][r][16B]
//    Direct strided global reads (coalesced across lanes), no LDS panel.
//    Also emits per-(qt,g,row) q2 partial sums (exact fp32).
__global__ __launch_bounds__(256) void q_convert(const float* __restrict__ emb,
                                                 uint4* __restrict__ qbt8,
                                                 float* __restrict__ q2p) {
    __shared__ float part[512];
    const int qt = blockIdx.x;           // 0..31
    const int g  = blockIdx.y;           // 0..11
    const int t  = threadIdx.x;
    const int b  = qt >> 3;
    const int p0 = (qt & 7) * 128;

    #pragma unroll
    for (int pass = 0; pass < 2; ++pass) {
        int idx = pass * 256 + t;          // bits [rg:2][h2:1][kc:1][r:5]
        int r  = idx & 31;
        int kc = (idx >> 5) & 1;
        int h2 = (idx >> 6) & 1;
        int rg = idx >> 7;
        int prow = rg * 32 + r;
        int kb = g * 64 + kc * 32 + h2 * 16;
        const float* src = emb + ((size_t)b * D + kb) * HW + p0 + prow;
        float v[16];
        float ss = 0.f;
        #pragma unroll
        for (int j = 0; j < 16; ++j) {
            v[j] = src[(size_t)j * HW];
            ss = fmaf(v[j], v[j], ss);
        }
        uint4 o;
        o.x = pack4_fp8(-2.f*v[0],  -2.f*v[1],  -2.f*v[2],  -2.f*v[3]);
        o.y = pack4_fp8(-2.f*v[4],  -2.f*v[5],  -2.f*v[6],  -2.f*v[7]);
        o.z = pack4_fp8(-2.f*v[8],  -2.f*v[9],  -2.f*v[10], -2.f*v[11]);
        o.w = pack4_fp8(-2.f*v[12], -2.f*v[13], -2.f*v[14], -2.f*v[15]);
        qbt8[((size_t)qt * KSTEPS + g) * 512 + idx] = o;
        part[idx] = ss;
    }
    __syncthreads();
    if (t < 128) {
        int rg = t >> 5, r = t & 31;
        int base = rg * 128 + r;
        float s = part[base] + part[base + 32] + part[base + 64] + part[base + 96];
        q2p[((size_t)qt * KSTEPS + g) * 128 + t] = s;
    }
}

// ---------------------------------------------------------------------------
// 3) MX-fp8 MFMA GEMM, BK=128 per barrier-pair (8 MFMA/sync), fused top-3.
//    score[n][m] = x2[n] - 2 db[n].q[m]  (-2 folded into q conversion)
__global__ __launch_bounds__(256, 4) void gemm_topk(const unsigned char* __restrict__ dbt8,
                                                    const unsigned char* __restrict__ qbt8,
                                                    const float* __restrict__ x2g,
                                                    float* __restrict__ partials) {
    __shared__ __align__(16) unsigned char As[2 * STEPB];   // 16 KB
    __shared__ __align__(16) unsigned char Bs[2 * STEPB];   // 16 KB
    __shared__ float X2s[BM];                               // 512 B
    __shared__ float red[2][BN][3];                         // 3 KB

    const int tid  = threadIdx.x;
    const int lane = tid & 63;
    const int w    = tid >> 6;
    const int wr   = w >> 1, wc = w & 1;
    const int h    = lane >> 5;          // k-chunk / row-half selector
    const int l31  = lane & 31;

    const int bid   = blockIdx.x;        // 0..1023
    const int xcd   = bid & 7;
    const int j     = bid >> 3;
    const int sp    = xcd + 8 * (j >> 5);
    const int qtile = j & 31;
    const int m0    = qtile * BN;

    // fragment LDS byte offsets within a step-block: rg*2048 + h2*1024 + kc*512 + r*16
    const int afrag = (wr * 2) * 2048 + h * 512 + l31 * 16;   // + i*2048 + h2*1024 + s*8192
    const int bfrag = (wc * 2) * 2048 + h * 512 + l31 * 16;

    const int lb = lane * 16;
    const unsigned char* qstep0 = qbt8 + (size_t)qtile * KSTEPS * STEPB + w * 2048 + lb;

    float t0[2], t1[2], t2[2];
    #pragma unroll
    for (int jj = 0; jj < 2; ++jj) { t0[jj] = INFINITY; t1[jj] = INFINITY; t2[jj] = INFINITY; }

    for (int tile = sp; tile < NT2; tile += NSPLIT) {
        const int n0 = tile * BM;
        const unsigned char* astep = dbt8 + (size_t)tile * KSTEPS * STEPB + w * 2048 + lb;
        const unsigned char* bstep = qstep0;

        f32x16 acc[2][2];
        #pragma unroll
        for (int i = 0; i < 2; ++i)
            #pragma unroll
            for (int jj = 0; jj < 2; ++jj)
                #pragma unroll
                for (int r = 0; r < 16; ++r) acc[i][jj][r] = 0.f;

        for (int g2 = 0; g2 < GSTEPS; ++g2) {
            __syncthreads();
            gl_lds16(astep,                As + w * 2048);
            gl_lds16(astep + 1024,         As + w * 2048 + 1024);
            gl_lds16(astep + STEPB,        As + 8192 + w * 2048);
            gl_lds16(astep + STEPB + 1024, As + 8192 + w * 2048 + 1024);
            gl_lds16(bstep,                Bs + w * 2048);
            gl_lds16(bstep + 1024,         Bs + w * 2048 + 1024);
            gl_lds16(bstep + STEPB,        Bs + 8192 + w * 2048);
            gl_lds16(bstep + STEPB + 1024, Bs + 8192 + w * 2048 + 1024);
            if (g2 == 0 && tid < BM) X2s[tid] = x2g[n0 + tid];
            astep += 2 * STEPB;
            bstep += 2 * STEPB;
            __syncthreads();

            #pragma unroll
            for (int s = 0; s < 2; ++s) {
                i32x8 af[2], bf[2];
                #pragma unroll
                for (int i = 0; i < 2; ++i) {
                    int4 lo = *(const int4*)(As + s * 8192 + afrag + i * 2048);
                    int4 hi = *(const int4*)(As + s * 8192 + afrag + i * 2048 + 1024);
                    af[i] = (i32x8){lo.x, lo.y, lo.z, lo.w, hi.x, hi.y, hi.z, hi.w};
                }
                #pragma unroll
                for (int jj = 0; jj < 2; ++jj) {
                    int4 lo = *(const int4*)(Bs + s * 8192 + bfrag + jj * 2048);
                    int4 hi = *(const int4*)(Bs + s * 8192 + bfrag + jj * 2048 + 1024);
                    bf[jj] = (i32x8){lo.x, lo.y, lo.z, lo.w, hi.x, hi.y, hi.z, hi.w};
                }
                #pragma unroll
                for (int i = 0; i < 2; ++i)
                    #pragma unroll
                    for (int jj = 0; jj < 2; ++jj)
                        acc[i][jj] = __builtin_amdgcn_mfma_scale_f32_32x32x64_f8f6f4(
                            af[i], bf[jj], acc[i][jj], 0, 0,
                            0, 0x7f7f7f7f, 0, 0x7f7f7f7f);
            }
        }

        // epilogue: s = x2[row] + acc  (rows: wr*64 + i*32 + rg2*8 + 4h + rr)
        #pragma unroll
        for (int i = 0; i < 2; ++i) {
            #pragma unroll
            for (int rg2 = 0; rg2 < 4; ++rg2) {
                float4 xv = *(const float4*)&X2s[wr * 64 + i * 32 + rg2 * 8 + 4 * h];
                #pragma unroll
                for (int jj = 0; jj < 2; ++jj) {
                    #pragma unroll
                    for (int rr = 0; rr < 4; ++rr) {
                        float s = acc[i][jj][rg2 * 4 + rr] + ((const float*)&xv)[rr];
                        insert3(t0[jj], t1[jj], t2[jj], s);
                    }
                }
            }
        }
    }

    // merge across the two row-halves (lane ^ 32), then across wr via LDS
    #pragma unroll
    for (int jj = 0; jj < 2; ++jj) {
        float o0 = __shfl_xor(t0[jj], 32);
        float o1 = __shfl_xor(t1[jj], 32);
        float o2 = __shfl_xor(t2[jj], 32);
        insert3(t0[jj], t1[jj], t2[jj], o0);
        insert3(t0[jj], t1[jj], t2[jj], o1);
        insert3(t0[jj], t1[jj], t2[jj], o2);
    }
    if (h == 0) {
        #pragma unroll
        for (int jj = 0; jj < 2; ++jj) {
            int col = wc * 64 + jj * 32 + l31;
            red[wr][col][0] = t0[jj];
            red[wr][col][1] = t1[jj];
            red[wr][col][2] = t2[jj];
        }
    }
    __syncthreads();
    if (tid < BN) {
        float a0 = red[0][tid][0], a1 = red[0][tid][1], a2 = red[0][tid][2];
        insert3(a0, a1, a2, red[1][tid][0]);
        insert3(a0, a1, a2, red[1][tid][1]);
        insert3(a0, a1, a2, red[1][tid][2]);
        float* dst = partials + ((size_t)(m0 + tid) * NSPLIT + sp) * 3;
        dst[0] = a0; dst[1] = a1; dst[2] = a2;
    }
}

// ---------------------------------------------------------------------------
// 4) merge partials, reduce q2 partials, add q2, sqrt, mean
__global__ __launch_bounds__(256) void merge_ood(const float* __restrict__ partials,
                                                 const float* __restrict__ q2p,
                                                 float* __restrict__ ood) {
    int m = blockIdx.x * 256 + threadIdx.x;
    if (m >= M) return;
    const float* pp = partials + (size_t)m * NSPLIT * 3;
    float a0 = INFINITY, a1 = INFINITY, a2 = INFINITY;
    #pragma unroll
    for (int j = 0; j < NSPLIT * 3; ++j) insert3(a0, a1, a2, pp[j]);
    const float* qp = q2p + (size_t)(m >> 7) * KSTEPS * 128 + (m & 127);
    float q = 0.f;
    #pragma unroll
    for (int g = 0; g < KSTEPS; ++g) q += qp[g * 128];
    float d0 = sqrtf(fmaxf(q + a0, 1e-12f));
    float d1 = sqrtf(fmaxf(q + a1, 1e-12f));
    float d2 = sqrtf(fmaxf(q + a2, 1e-12f));
    ood[m] = (d0 + d1 + d2) * (1.f / 3.f);
}

// ---------------------------------------------------------------------------
// 5) half-pixel bilinear 32x32 -> 512x512
__global__ __launch_bounds__(256) void upsample(const float* __restrict__ ood,
                                                float* __restrict__ out) {
    int idx = blockIdx.x * 256 + threadIdx.x;
    int ox = idx & (OUTW - 1);
    int oy = (idx >> 9) & (OUTH - 1);
    int bb = idx >> 18;
    float sx = (ox + 0.5f) * (32.f / OUTW) - 0.5f;
    float sy = (oy + 0.5f) * (32.f / OUTH) - 0.5f;
    float fx = floorf(sx), fy = floorf(sy);
    float wx = sx - fx, wy = sy - fy;
    int x0 = max(0, min(31, (int)fx));
    int x1 = max(0, min(31, (int)fx + 1));
    int y0 = max(0, min(31, (int)fy));
    int y1 = max(0, min(31, (int)fy + 1));
    const float* src = ood + bb * 1024;
    float v00 = src[y0 * 32 + x0];
    float v01 = src[y0 * 32 + x1];
    float v10 = src[y1 * 32 + x0];
    float v11 = src[y1 * 32 + x1];
    float top = v00 + wx * (v01 - v00);
    float bot = v10 + wx * (v11 - v10);
    out[idx] = top + wy * (bot - top);
}

// ---------------------------------------------------------------------------
extern "C" void kernel_launch(void* const* d_in, const int* in_sizes, int n_in,
                              void* d_out, int out_size, void* d_ws, size_t ws_size,
                              hipStream_t stream) {
    const float* emb = (const float*)d_in[0];
    const float* db  = (const float*)d_in[1];
    float* out = (float*)d_out;

    // workspace layout (bytes), total ~21.4 MB
    char* ws = (char*)d_ws;
    unsigned char* dbt8 = (unsigned char*)ws;                    // 157*12*8192 = 15,433,728
    unsigned char* qbt8 = (unsigned char*)(ws + 15433728);       // 32*12*8192  =  3,145,728
    float* x2       = (float*)(ws + 18579456);                   // 20096*4 = 80,384
    float* x2p      = (float*)(ws + 18659840);                   // 157*12*128*4 = 964,608
    float* q2p      = (float*)(ws + 19624448);                   // 32*12*128*4 = 196,608
    float* ood      = (float*)(ws + 19821056);                   // 16,384
    float* partials = (float*)(ws + 19837440);                   // 4096*32*3*4 = 1,572,864

    db_convert<<<dim3(NT2, KSTEPS), 256, 0, stream>>>(db, (uint4*)dbt8, x2p);
    q_convert<<<dim3(32, KSTEPS), 256, 0, stream>>>(emb, (uint4*)qbt8, q2p);
    x2_reduce<<<(NDBP + 255) / 256, 256, 0, stream>>>(x2p, x2);
    gemm_topk<<<NSPLIT * 32, 256, 0, stream>>>(dbt8, qbt8, x2, partials);
    merge_ood<<<(M + 255) / 256, 256, 0, stream>>>(partials, q2p, ood);
    upsample<<<(B * OUTH * OUTW) / 256, 256, 0, stream>>>(ood, out);
}

// Round 6
// 184.395 us; speedup vs baseline: 12.5463x; 1.1585x over previous
//
#include <hip/hip_runtime.h>
#include <hip/hip_bf16.h>
#include <math.h>

// Problem constants
constexpr int B    = 4;
constexpr int D    = 768;
constexpr int HW   = 1024;
constexpr int M    = B * HW;        // 4096 queries
constexpr int NDB  = 20000;
constexpr int LT   = 158;           // 128-row layout tiles (20224 rows padded)
constexpr int NDBP = LT * 128;      // 20224
constexpr int OUTH = 512;
constexpr int OUTW = 512;

constexpr int BM     = 256;         // db rows per gemm tile (2 layout tiles)
constexpr int BN     = 128;         // queries per tile
constexpr int KSTEPS = D / 64;      // 12 64-K step-blocks in the tiled layout
constexpr int GSTEPS = KSTEPS / 2;  // 6 barrier-pairs per tile (BK=128)
constexpr int NSPLIT = 16;
constexpr int NT2    = 79;          // 256-row gemm tiles
constexpr int STEPB  = 128 * 64;    // 8192 bytes per 64-K step-block

typedef int   i32x8  __attribute__((ext_vector_type(8)));
typedef float f32x16 __attribute__((ext_vector_type(16)));

__device__ __forceinline__ void insert3(float& t0, float& t1, float& t2, float d) {
    float a0 = fminf(d, t0);
    float b0 = fmaxf(d, t0);
    float a1 = fminf(b0, t1);
    float b1 = fmaxf(b0, t1);
    t0 = a0; t1 = a1;
    t2 = fminf(b1, t2);
}

__device__ __forceinline__ unsigned int pack4_fp8(float a, float b, float c, float d) {
    int v = __builtin_amdgcn_cvt_pk_fp8_f32(a, b, 0, false);
    v = __builtin_amdgcn_cvt_pk_fp8_f32(c, d, v, true);
    return (unsigned int)v;
}

__device__ __forceinline__ void gl_lds16(const unsigned char* g, unsigned char* l) {
    __builtin_amdgcn_global_load_lds(
        (const __attribute__((address_space(1))) void*)g,
        (__attribute__((address_space(3))) void*)l, 16, 0, 0);
}

// ---------------------------------------------------------------------------
// 1) db [20000][768] fp32 -> fp8 tiled [158][12][rg 4][h2 2][kc 2][r 32][16B]
//    Coalesced float4 loads -> LDS panel (stride 65: conflict-free) -> pack.
//    Also per-(tile,g,row) x2 partials.
__global__ __launch_bounds__(256) void db_convert(const float* __restrict__ db,
                                                  uint4* __restrict__ dbt8,
                                                  float* __restrict__ x2p) {
    __shared__ float panel[128][65];
    __shared__ float part[512];
    const int lt = blockIdx.x;
    const int g  = blockIdx.y;
    const int t  = threadIdx.x;
    const int n0 = lt * 128;

    #pragma unroll
    for (int pass = 0; pass < 8; ++pass) {
        int idx = pass * 256 + t;            // 0..2047
        int row = idx >> 4, c4 = idx & 15;
        int n = n0 + row;
        float4 v = make_float4(0.f, 0.f, 0.f, 0.f);
        if (n < NDB) v = *(const float4*)(db + (size_t)n * D + g * 64 + c4 * 4);
        panel[row][c4 * 4 + 0] = v.x;
        panel[row][c4 * 4 + 1] = v.y;
        panel[row][c4 * 4 + 2] = v.z;
        panel[row][c4 * 4 + 3] = v.w;
    }
    __syncthreads();
    #pragma unroll
    for (int pass = 0; pass < 2; ++pass) {
        int idx = pass * 256 + t;            // bits [rg:2][h2:1][kc:1][r:5]
        int r  = idx & 31;
        int kc = (idx >> 5) & 1;
        int h2 = (idx >> 6) & 1;
        int rg = idx >> 7;
        int row  = rg * 32 + r;
        int kloc = kc * 32 + h2 * 16;
        float v[16];
        float ss = 0.f;
        #pragma unroll
        for (int j = 0; j < 16; ++j) {
            v[j] = panel[row][kloc + j];
            ss = fmaf(v[j], v[j], ss);
        }
        uint4 o;
        o.x = pack4_fp8(v[0],  v[1],  v[2],  v[3]);
        o.y = pack4_fp8(v[4],  v[5],  v[6],  v[7]);
        o.z = pack4_fp8(v[8],  v[9],  v[10], v[11]);
        o.w = pack4_fp8(v[12], v[13], v[14], v[15]);
        dbt8[((size_t)lt * KSTEPS + g) * 512 + idx] = o;
        part[idx] = ss;
    }
    __syncthreads();
    if (t < 128) {
        int base = (t >> 5) * 128 + (t & 31);
        float s = part[base] + part[base + 32] + part[base + 64] + part[base + 96];
        x2p[((size_t)lt * KSTEPS + g) * 128 + t] = s;
    }
}

// 1b) reduce 12 x2 partials -> x2[n]; pad rows get 1e30
__global__ __launch_bounds__(256) void x2_reduce(const float* __restrict__ x2p,
                                                 float* __restrict__ x2) {
    int n = blockIdx.x * 256 + threadIdx.x;
    if (n >= NDBP) return;
    if (n >= NDB) { x2[n] = 1e30f; return; }
    const float* p = x2p + (size_t)(n >> 7) * KSTEPS * 128 + (n & 127);
    float s = 0.f;
    #pragma unroll
    for (int g = 0; g < KSTEPS; ++g) s += p[g * 128];
    x2[n] = s;
}

// ---------------------------------------------------------------------------
// 2) emb [4][768][1024] -> fp8 (-2*q) tiled [32][12][rg][h2][kc][r][16B]
//    Strided-but-coalesced reads; per-(qt,g,row) q2 partials.
__global__ __launch_bounds__(256) void q_convert(const float* __restrict__ emb,
                                                 uint4* __restrict__ qbt8,
                                                 float* __restrict__ q2p) {
    __shared__ float part[512];
    const int qt = blockIdx.x;           // 0..31
    const int g  = blockIdx.y;           // 0..11
    const int t  = threadIdx.x;
    const int b  = qt >> 3;
    const int p0 = (qt & 7) * 128;

    #pragma unroll
    for (int pass = 0; pass < 2; ++pass) {
        int idx = pass * 256 + t;          // bits [rg:2][h2:1][kc:1][r:5]
        int r  = idx & 31;
        int kc = (idx >> 5) & 1;
        int h2 = (idx >> 6) & 1;
        int rg = idx >> 7;
        int prow = rg * 32 + r;
        int kb = g * 64 + kc * 32 + h2 * 16;
        const float* src = emb + ((size_t)b * D + kb) * HW + p0 + prow;
        float v[16];
        float ss = 0.f;
        #pragma unroll
        for (int j = 0; j < 16; ++j) {
            v[j] = src[(size_t)j * HW];
            ss = fmaf(v[j], v[j], ss);
        }
        uint4 o;
        o.x = pack4_fp8(-2.f*v[0],  -2.f*v[1],  -2.f*v[2],  -2.f*v[3]);
        o.y = pack4_fp8(-2.f*v[4],  -2.f*v[5],  -2.f*v[6],  -2.f*v[7]);
        o.z = pack4_fp8(-2.f*v[8],  -2.f*v[9],  -2.f*v[10], -2.f*v[11]);
        o.w = pack4_fp8(-2.f*v[12], -2.f*v[13], -2.f*v[14], -2.f*v[15]);
        qbt8[((size_t)qt * KSTEPS + g) * 512 + idx] = o;
        part[idx] = ss;
    }
    __syncthreads();
    if (t < 128) {
        int base = (t >> 5) * 128 + (t & 31);
        float s = part[base] + part[base + 32] + part[base + 64] + part[base + 96];
        q2p[((size_t)qt * KSTEPS + g) * 128 + t] = s;
    }
}

// ---------------------------------------------------------------------------
// 3) MX-fp8 MFMA GEMM, 256x128 tile, BK=128 per barrier-pair, fused top-3.
//    Wave w owns rows [w*64, w*64+64) x all 128 cols: acc[2][4].
__global__ __launch_bounds__(256, 2) void gemm_topk(const unsigned char* __restrict__ dbt8,
                                                    const unsigned char* __restrict__ qbt8,
                                                    const float* __restrict__ x2g,
                                                    float* __restrict__ partials) {
    __shared__ __align__(16) unsigned char As[4 * STEPB];   // 32 KB [w-chunk][8192]
    __shared__ __align__(16) unsigned char Bs[2 * STEPB];   // 16 KB [gs][8192]
    __shared__ float X2s[BM];                               // 1 KB
    __shared__ float red[4][BN][3];                         // 6 KB

    const int tid  = threadIdx.x;
    const int lane = tid & 63;
    const int w    = tid >> 6;           // 0..3
    const int lts  = w >> 1;             // which 128-row layout half
    const int wr   = w & 1;
    const int h    = lane >> 5;
    const int l31  = lane & 31;

    const int bid   = blockIdx.x;        // 0..511
    const int xcd   = bid & 7;
    const int j     = bid >> 3;          // 0..63
    const int sp    = xcd + 8 * (j >> 5);  // 0..15
    const int qtile = j & 31;
    const int m0    = qtile * BN;

    // fragment offsets: As[(lts*2+s)*8192 + (wr*2+i)*2048 + h*512 + l31*16]
    int a_off[2], b_off[4];
    #pragma unroll
    for (int i = 0; i < 2; ++i) a_off[i] = lts * 16384 + (wr * 2 + i) * 2048 + h * 512 + l31 * 16;
    #pragma unroll
    for (int j4 = 0; j4 < 4; ++j4) b_off[j4] = j4 * 2048 + h * 512 + l31 * 16;

    const int lb = lane * 16;
    // B staging: wave w loads quarter: step g = 2*g2 + (w>>1), half (w&1)
    const unsigned char* qstep0 = qbt8 + ((size_t)qtile * KSTEPS + lts) * STEPB + wr * 4096 + lb;
    unsigned char* bdst = Bs + lts * 8192 + wr * 4096;
    unsigned char* adst = As + w * 8192;

    float t0[4], t1[4], t2[4];
    #pragma unroll
    for (int j4 = 0; j4 < 4; ++j4) { t0[j4] = INFINITY; t1[j4] = INFINITY; t2[j4] = INFINITY; }

    for (int tile = sp; tile < NT2; tile += NSPLIT) {
        const int n0 = tile * BM;
        // A staging: wave w covers layout tile 2*tile+lts, step 2*g2+wr
        const unsigned char* astep = dbt8 + (((size_t)(2 * tile + lts) * KSTEPS) + wr) * STEPB + lb;
        const unsigned char* bstep = qstep0;

        f32x16 acc[2][4];
        #pragma unroll
        for (int i = 0; i < 2; ++i)
            #pragma unroll
            for (int j4 = 0; j4 < 4; ++j4)
                #pragma unroll
                for (int r = 0; r < 16; ++r) acc[i][j4][r] = 0.f;

        for (int g2 = 0; g2 < GSTEPS; ++g2) {
            __syncthreads();
            #pragma unroll
            for (int l = 0; l < 8; ++l) gl_lds16(astep + l * 1024, adst + l * 1024);
            #pragma unroll
            for (int l = 0; l < 4; ++l) gl_lds16(bstep + l * 1024, bdst + l * 1024);
            if (g2 == 0) X2s[tid] = x2g[n0 + tid];
            astep += 2 * STEPB;
            bstep += 2 * STEPB;
            __syncthreads();

            #pragma unroll
            for (int s = 0; s < 2; ++s) {
                i32x8 af[2], bf[4];
                #pragma unroll
                for (int i = 0; i < 2; ++i) {
                    int4 lo = *(const int4*)(As + s * 8192 + a_off[i]);
                    int4 hi = *(const int4*)(As + s * 8192 + a_off[i] + 1024);
                    af[i] = (i32x8){lo.x, lo.y, lo.z, lo.w, hi.x, hi.y, hi.z, hi.w};
                }
                #pragma unroll
                for (int j4 = 0; j4 < 4; ++j4) {
                    int4 lo = *(const int4*)(Bs + s * 8192 + b_off[j4]);
                    int4 hi = *(const int4*)(Bs + s * 8192 + b_off[j4] + 1024);
                    bf[j4] = (i32x8){lo.x, lo.y, lo.z, lo.w, hi.x, hi.y, hi.z, hi.w};
                }
                #pragma unroll
                for (int i = 0; i < 2; ++i)
                    #pragma unroll
                    for (int j4 = 0; j4 < 4; ++j4)
                        acc[i][j4] = __builtin_amdgcn_mfma_scale_f32_32x32x64_f8f6f4(
                            af[i], bf[j4], acc[i][j4], 0, 0,
                            0, 0x7f7f7f7f, 0, 0x7f7f7f7f);
            }
        }

        // epilogue: rows = w*64 + i*32 + rg2*8 + 4h + rr
        #pragma unroll
        for (int i = 0; i < 2; ++i) {
            #pragma unroll
            for (int rg2 = 0; rg2 < 4; ++rg2) {
                float4 xv = *(const float4*)&X2s[w * 64 + i * 32 + rg2 * 8 + 4 * h];
                #pragma unroll
                for (int j4 = 0; j4 < 4; ++j4) {
                    #pragma unroll
                    for (int rr = 0; rr < 4; ++rr) {
                        float s = acc[i][j4][rg2 * 4 + rr] + ((const float*)&xv)[rr];
                        insert3(t0[j4], t1[j4], t2[j4], s);
                    }
                }
            }
        }
    }

    // merge across row-halves (lane^32; col = l31 is preserved)
    #pragma unroll
    for (int j4 = 0; j4 < 4; ++j4) {
        float o0 = __shfl_xor(t0[j4], 32);
        float o1 = __shfl_xor(t1[j4], 32);
        float o2 = __shfl_xor(t2[j4], 32);
        insert3(t0[j4], t1[j4], t2[j4], o0);
        insert3(t0[j4], t1[j4], t2[j4], o1);
        insert3(t0[j4], t1[j4], t2[j4], o2);
    }
    if (h == 0) {
        #pragma unroll
        for (int j4 = 0; j4 < 4; ++j4) {
            int col = j4 * 32 + l31;
            red[w][col][0] = t0[j4];
            red[w][col][1] = t1[j4];
            red[w][col][2] = t2[j4];
        }
    }
    __syncthreads();
    if (tid < BN) {
        float a0 = red[0][tid][0], a1 = red[0][tid][1], a2 = red[0][tid][2];
        #pragma unroll
        for (int ww = 1; ww < 4; ++ww) {
            insert3(a0, a1, a2, red[ww][tid][0]);
            insert3(a0, a1, a2, red[ww][tid][1]);
            insert3(a0, a1, a2, red[ww][tid][2]);
        }
        float* dst = partials + ((size_t)(m0 + tid) * NSPLIT + sp) * 3;
        dst[0] = a0; dst[1] = a1; dst[2] = a2;
    }
}

// ---------------------------------------------------------------------------
// 4) merge partials, reduce q2 partials, sqrt, mean
__global__ __launch_bounds__(256) void merge_ood(const float* __restrict__ partials,
                                                 const float* __restrict__ q2p,
                                                 float* __restrict__ ood) {
    int m = blockIdx.x * 256 + threadIdx.x;
    if (m >= M) return;
    const float* pp = partials + (size_t)m * NSPLIT * 3;
    float a0 = INFINITY, a1 = INFINITY, a2 = INFINITY;
    #pragma unroll
    for (int j = 0; j < NSPLIT * 3; ++j) insert3(a0, a1, a2, pp[j]);
    const float* qp = q2p + (size_t)(m >> 7) * KSTEPS * 128 + (m & 127);
    float q = 0.f;
    #pragma unroll
    for (int g = 0; g < KSTEPS; ++g) q += qp[g * 128];
    float d0 = sqrtf(fmaxf(q + a0, 1e-12f));
    float d1 = sqrtf(fmaxf(q + a1, 1e-12f));
    float d2 = sqrtf(fmaxf(q + a2, 1e-12f));
    ood[m] = (d0 + d1 + d2) * (1.f / 3.f);
}

// ---------------------------------------------------------------------------
// 5) half-pixel bilinear 32x32 -> 512x512
__global__ __launch_bounds__(256) void upsample(const float* __restrict__ ood,
                                                float* __restrict__ out) {
    int idx = blockIdx.x * 256 + threadIdx.x;
    int ox = idx & (OUTW - 1);
    int oy = (idx >> 9) & (OUTH - 1);
    int bb = idx >> 18;
    float sx = (ox + 0.5f) * (32.f / OUTW) - 0.5f;
    float sy = (oy + 0.5f) * (32.f / OUTH) - 0.5f;
    float fx = floorf(sx), fy = floorf(sy);
    float wx = sx - fx, wy = sy - fy;
    int x0 = max(0, min(31, (int)fx));
    int x1 = max(0, min(31, (int)fx + 1));
    int y0 = max(0, min(31, (int)fy));
    int y1 = max(0, min(31, (int)fy + 1));
    const float* src = ood + bb * 1024;
    float v00 = src[y0 * 32 + x0];
    float v01 = src[y0 * 32 + x1];
    float v10 = src[y1 * 32 + x0];
    float v11 = src[y1 * 32 + x1];
    float top = v00 + wx * (v01 - v00);
    float bot = v10 + wx * (v11 - v10);
    out[idx] = top + wy * (bot - top);
}

// ---------------------------------------------------------------------------
extern "C" void kernel_launch(void* const* d_in, const int* in_sizes, int n_in,
                              void* d_out, int out_size, void* d_ws, size_t ws_size,
                              hipStream_t stream) {
    const float* emb = (const float*)d_in[0];
    const float* db  = (const float*)d_in[1];
    float* out = (float*)d_out;

    // workspace layout (bytes), total ~20.7 MB
    char* ws = (char*)d_ws;
    unsigned char* dbt8 = (unsigned char*)ws;                    // 158*12*8192 = 15,532,032
    unsigned char* qbt8 = (unsigned char*)(ws + 15532032);       // 32*12*8192  =  3,145,728
    float* x2       = (float*)(ws + 18677760);                   // 20224*4 = 80,896
    float* x2p      = (float*)(ws + 18758656);                   // 158*12*128*4 = 970,752
    float* q2p      = (float*)(ws + 19729408);                   // 32*12*128*4 = 196,608
    float* ood      = (float*)(ws + 19926016);                   // 16,384
    float* partials = (float*)(ws + 19942400);                   // 4096*16*3*4 = 786,432

    db_convert<<<dim3(LT, KSTEPS), 256, 0, stream>>>(db, (uint4*)dbt8, x2p);
    q_convert<<<dim3(32, KSTEPS), 256, 0, stream>>>(emb, (uint4*)qbt8, q2p);
    x2_reduce<<<(NDBP + 255) / 256, 256, 0, stream>>>(x2p, x2);
    gemm_topk<<<NSPLIT * 32, 256, 0, stream>>>(dbt8, qbt8, x2, partials);
    merge_ood<<<(M + 255) / 256, 256, 0, stream>>>(partials, q2p, ood);
    upsample<<<(B * OUTH * OUTW) / 256, 256, 0, stream>>>(ood, out);
}

// Round 7
// 184.362 us; speedup vs baseline: 12.5486x; 1.0002x over previous
//
#include <hip/hip_runtime.h>
#include <hip/hip_bf16.h>
#include <math.h>

// Problem constants
constexpr int B    = 4;
constexpr int D    = 768;
constexpr int HW   = 1024;
constexpr int M    = B * HW;        // 4096 queries
constexpr int NDB  = 20000;
constexpr int LT   = 158;           // 128-row layout tiles (20224 rows padded)
constexpr int NDBP = LT * 128;      // 20224
constexpr int OUTH = 512;
constexpr int OUTW = 512;

constexpr int BM     = 256;         // db rows per gemm tile (2 layout tiles)
constexpr int BN     = 128;         // queries per tile
constexpr int KSTEPS = D / 64;      // 12 64-K steps
constexpr int NSPLIT = 16;
constexpr int NT2    = 79;          // 256-row gemm tiles
constexpr int STEPB  = 128 * 64;    // 8192 B per 64-K step-block (one layout tile)

typedef int   i32x8  __attribute__((ext_vector_type(8)));
typedef float f32x16 __attribute__((ext_vector_type(16)));

__device__ __forceinline__ void insert3(float& t0, float& t1, float& t2, float d) {
    float a0 = fminf(d, t0);
    float b0 = fmaxf(d, t0);
    float a1 = fminf(b0, t1);
    float b1 = fmaxf(b0, t1);
    t0 = a0; t1 = a1;
    t2 = fminf(b1, t2);
}

__device__ __forceinline__ unsigned int pack4_fp8(float a, float b, float c, float d) {
    int v = __builtin_amdgcn_cvt_pk_fp8_f32(a, b, 0, false);
    v = __builtin_amdgcn_cvt_pk_fp8_f32(c, d, v, true);
    return (unsigned int)v;
}

__device__ __forceinline__ void gl_lds16(const unsigned char* g, unsigned char* l) {
    __builtin_amdgcn_global_load_lds(
        (const __attribute__((address_space(1))) void*)g,
        (__attribute__((address_space(3))) void*)l, 16, 0, 0);
}

// ---------------------------------------------------------------------------
// 1) db [20000][768] fp32 -> fp8 tiled [158][12][rg 4][h2 2][kc 2][r 32][16B]
//    Coalesced float4 loads -> LDS panel (stride 68: 16B-aligned rows, float4
//    transpose reads) -> pack. Also per-(tile,g,row) x2 partials.
__global__ __launch_bounds__(256) void db_convert(const float* __restrict__ db,
                                                  uint4* __restrict__ dbt8,
                                                  float* __restrict__ x2p) {
    __shared__ float panel[128][68];
    __shared__ float part[512];
    const int lt = blockIdx.x;
    const int g  = blockIdx.y;
    const int t  = threadIdx.x;
    const int n0 = lt * 128;

    #pragma unroll
    for (int pass = 0; pass < 8; ++pass) {
        int idx = pass * 256 + t;            // 0..2047
        int row = idx >> 4, c4 = idx & 15;
        int n = n0 + row;
        float4 v = make_float4(0.f, 0.f, 0.f, 0.f);
        if (n < NDB) v = *(const float4*)(db + (size_t)n * D + g * 64 + c4 * 4);
        *(float4*)&panel[row][c4 * 4] = v;
    }
    __syncthreads();
    #pragma unroll
    for (int pass = 0; pass < 2; ++pass) {
        int idx = pass * 256 + t;            // bits [rg:2][h2:1][kc:1][r:5]
        int r  = idx & 31;
        int kc = (idx >> 5) & 1;
        int h2 = (idx >> 6) & 1;
        int rg = idx >> 7;
        int row  = rg * 32 + r;
        int kloc = kc * 32 + h2 * 16;
        float4 va = *(const float4*)&panel[row][kloc + 0];
        float4 vb = *(const float4*)&panel[row][kloc + 4];
        float4 vc = *(const float4*)&panel[row][kloc + 8];
        float4 vd = *(const float4*)&panel[row][kloc + 12];
        float ss = va.x*va.x + va.y*va.y + va.z*va.z + va.w*va.w
                 + vb.x*vb.x + vb.y*vb.y + vb.z*vb.z + vb.w*vb.w
                 + vc.x*vc.x + vc.y*vc.y + vc.z*vc.z + vc.w*vc.w
                 + vd.x*vd.x + vd.y*vd.y + vd.z*vd.z + vd.w*vd.w;
        uint4 o;
        o.x = pack4_fp8(va.x, va.y, va.z, va.w);
        o.y = pack4_fp8(vb.x, vb.y, vb.z, vb.w);
        o.z = pack4_fp8(vc.x, vc.y, vc.z, vc.w);
        o.w = pack4_fp8(vd.x, vd.y, vd.z, vd.w);
        dbt8[((size_t)lt * KSTEPS + g) * 512 + idx] = o;
        part[idx] = ss;
    }
    __syncthreads();
    if (t < 128) {
        int base = (t >> 5) * 128 + (t & 31);
        float s = part[base] + part[base + 32] + part[base + 64] + part[base + 96];
        x2p[((size_t)lt * KSTEPS + g) * 128 + t] = s;
    }
}

// ---------------------------------------------------------------------------
// 2) emb [4][768][1024] -> fp8 (-2*q) tiled [32][12][rg][h2][kc][r][16B]
//    Strided-but-coalesced reads; per-(qt,g,row) q2 partials.
__global__ __launch_bounds__(256) void q_convert(const float* __restrict__ emb,
                                                 uint4* __restrict__ qbt8,
                                                 float* __restrict__ q2p) {
    __shared__ float part[512];
    const int qt = blockIdx.x;           // 0..31
    const int g  = blockIdx.y;           // 0..11
    const int t  = threadIdx.x;
    const int b  = qt >> 3;
    const int p0 = (qt & 7) * 128;

    #pragma unroll
    for (int pass = 0; pass < 2; ++pass) {
        int idx = pass * 256 + t;          // bits [rg:2][h2:1][kc:1][r:5]
        int r  = idx & 31;
        int kc = (idx >> 5) & 1;
        int h2 = (idx >> 6) & 1;
        int rg = idx >> 7;
        int prow = rg * 32 + r;
        int kb = g * 64 + kc * 32 + h2 * 16;
        const float* src = emb + ((size_t)b * D + kb) * HW + p0 + prow;
        float v[16];
        float ss = 0.f;
        #pragma unroll
        for (int j = 0; j < 16; ++j) {
            v[j] = src[(size_t)j * HW];
            ss = fmaf(v[j], v[j], ss);
        }
        uint4 o;
        o.x = pack4_fp8(-2.f*v[0],  -2.f*v[1],  -2.f*v[2],  -2.f*v[3]);
        o.y = pack4_fp8(-2.f*v[4],  -2.f*v[5],  -2.f*v[6],  -2.f*v[7]);
        o.z = pack4_fp8(-2.f*v[8],  -2.f*v[9],  -2.f*v[10], -2.f*v[11]);
        o.w = pack4_fp8(-2.f*v[12], -2.f*v[13], -2.f*v[14], -2.f*v[15]);
        qbt8[((size_t)qt * KSTEPS + g) * 512 + idx] = o;
        part[idx] = ss;
    }
    __syncthreads();
    if (t < 128) {
        int base = (t >> 5) * 128 + (t & 31);
        float s = part[base] + part[base + 32] + part[base + 64] + part[base + 96];
        q2p[((size_t)qt * KSTEPS + g) * 128 + t] = s;
    }
}

// ---------------------------------------------------------------------------
// 3) MX-fp8 MFMA GEMM, 256x128 tile, software-pipelined LDS double-buffer:
//    one barrier per 64-K step; stage(g+1) issued right after the barrier,
//    compute(g) follows -> the vmcnt(0) at the NEXT barrier waits on a load
//    that had a full compute phase to land.
//    Hazards: barrier(g) guarantees (a) stage(g) landed [vmcnt0], (b) all
//    waves finished ds_reads of buf[g-1] [lgkmcnt0] before stage(g+1)
//    overwrites it. x2_reduce fused into the per-tile X2s fill.
__global__ __launch_bounds__(256, 2) void gemm_topk(const unsigned char* __restrict__ dbt8,
                                                    const unsigned char* __restrict__ qbt8,
                                                    const float* __restrict__ x2p,
                                                    float* __restrict__ partials) {
    __shared__ __align__(16) unsigned char Asm[2 * 16384];  // [buf][half][rg][h2][kc][r][16]
    __shared__ __align__(16) unsigned char Bsm[2 * 8192];   // [buf][rg][h2][kc][r][16]
    __shared__ float X2s[BM];                               // 1 KB
    __shared__ float red[4][BN][3];                         // 6 KB

    const int tid  = threadIdx.x;
    const int lane = tid & 63;
    const int w    = tid >> 6;           // 0..3
    const int lts  = w >> 1;             // 128-row layout half
    const int wr   = w & 1;
    const int h    = lane >> 5;
    const int l31  = lane & 31;

    const int bid   = blockIdx.x;        // 0..511
    const int xcd   = bid & 7;
    const int j     = bid >> 3;
    const int sp    = xcd + 8 * (j >> 5);   // 0..15
    const int qtile = j & 31;
    const int m0    = qtile * BN;

    // fragment byte offsets within one buffer
    int a_off[2], b_off[4];
    #pragma unroll
    for (int i = 0; i < 2; ++i) a_off[i] = lts * 8192 + (wr * 2 + i) * 2048 + h * 512 + l31 * 16;
    #pragma unroll
    for (int j4 = 0; j4 < 4; ++j4) b_off[j4] = j4 * 2048 + h * 512 + l31 * 16;

    // staging pointers at (tile=sp, g=0); wave w stages A-quarter (half lts,
    // portion wr) and B-eighth w.
    const unsigned char* aNext = dbt8 + (size_t)(2 * sp + lts) * KSTEPS * STEPB + wr * 4096 + lane * 16;
    const unsigned char* bNext = qbt8 + (size_t)qtile * KSTEPS * STEPB + w * 2048 + lane * 16;
    unsigned char* aDst = Asm + w * 4096;   // +buf*16384
    unsigned char* bDst = Bsm + w * 2048;   // +buf*8192

    // prologue: stage (sp, 0) into buf 0
    #pragma unroll
    for (int l = 0; l < 4; ++l) gl_lds16(aNext + l * 1024, aDst + l * 1024);
    #pragma unroll
    for (int l = 0; l < 2; ++l) gl_lds16(bNext + l * 1024, bDst + l * 1024);

    float t0[4], t1[4], t2[4];
    #pragma unroll
    for (int j4 = 0; j4 < 4; ++j4) { t0[j4] = INFINITY; t1[j4] = INFINITY; t2[j4] = INFINITY; }

    for (int tile = sp; tile < NT2; tile += NSPLIT) {
        __syncthreads();   // (A) previous tile's epilogue done reading X2s
        {   // fused x2 reduction: X2s[row] = sum of 12 partials (pad -> 1e30)
            int n = tile * BM + tid;
            float s = 1e30f;
            if (n < NDB) {
                const float* p = x2p + (size_t)(n >> 7) * (KSTEPS * 128) + (n & 127);
                s = 0.f;
                #pragma unroll
                for (int g = 0; g < KSTEPS; ++g) s += p[g * 128];
            }
            X2s[tid] = s;
        }

        f32x16 acc[2][4];
        #pragma unroll
        for (int i = 0; i < 2; ++i)
            #pragma unroll
            for (int j4 = 0; j4 < 4; ++j4)
                #pragma unroll
                for (int r = 0; r < 16; ++r) acc[i][j4][r] = 0.f;

        const bool lastTile = (tile + NSPLIT >= NT2);

        #pragma unroll 2
        for (int g = 0; g < KSTEPS; ++g) {
            const int cur = g & 1;
            __syncthreads();   // stage(g) landed; buf[cur^1] readers done
            // issue stage(g+1) into the other buffer
            if (g < KSTEPS - 1) {
                aNext += STEPB;
                bNext += STEPB;
                unsigned char* ad = aDst + (cur ^ 1) * 16384;
                unsigned char* bd = bDst + (cur ^ 1) * 8192;
                #pragma unroll
                for (int l = 0; l < 4; ++l) gl_lds16(aNext + l * 1024, ad + l * 1024);
                #pragma unroll
                for (int l = 0; l < 2; ++l) gl_lds16(bNext + l * 1024, bd + l * 1024);
            } else if (!lastTile) {
                aNext += (size_t)(2 * NSPLIT) * KSTEPS * STEPB - (KSTEPS - 1) * STEPB;
                bNext -= (size_t)(KSTEPS - 1) * STEPB;
                unsigned char* ad = aDst + (cur ^ 1) * 16384;
                unsigned char* bd = bDst + (cur ^ 1) * 8192;
                #pragma unroll
                for (int l = 0; l < 4; ++l) gl_lds16(aNext + l * 1024, ad + l * 1024);
                #pragma unroll
                for (int l = 0; l < 2; ++l) gl_lds16(bNext + l * 1024, bd + l * 1024);
            }
            // compute step g from buf[cur]
            const unsigned char* Ab = Asm + cur * 16384;
            const unsigned char* Bb = Bsm + cur * 8192;
            i32x8 af[2], bf[4];
            #pragma unroll
            for (int i = 0; i < 2; ++i) {
                int4 lo = *(const int4*)(Ab + a_off[i]);
                int4 hi = *(const int4*)(Ab + a_off[i] + 1024);
                af[i] = (i32x8){lo.x, lo.y, lo.z, lo.w, hi.x, hi.y, hi.z, hi.w};
            }
            #pragma unroll
            for (int j4 = 0; j4 < 4; ++j4) {
                int4 lo = *(const int4*)(Bb + b_off[j4]);
                int4 hi = *(const int4*)(Bb + b_off[j4] + 1024);
                bf[j4] = (i32x8){lo.x, lo.y, lo.z, lo.w, hi.x, hi.y, hi.z, hi.w};
            }
            #pragma unroll
            for (int i = 0; i < 2; ++i)
                #pragma unroll
                for (int j4 = 0; j4 < 4; ++j4)
                    acc[i][j4] = __builtin_amdgcn_mfma_scale_f32_32x32x64_f8f6f4(
                        af[i], bf[j4], acc[i][j4], 0, 0,
                        0, 0x7f7f7f7f, 0, 0x7f7f7f7f);
        }

        // epilogue: rows = w*64 + i*32 + rg2*8 + 4h + rr  (reads X2s before (A))
        #pragma unroll
        for (int i = 0; i < 2; ++i) {
            #pragma unroll
            for (int rg2 = 0; rg2 < 4; ++rg2) {
                float4 xv = *(const float4*)&X2s[w * 64 + i * 32 + rg2 * 8 + 4 * h];
                #pragma unroll
                for (int j4 = 0; j4 < 4; ++j4) {
                    #pragma unroll
                    for (int rr = 0; rr < 4; ++rr) {
                        float s = acc[i][j4][rg2 * 4 + rr] + ((const float*)&xv)[rr];
                        insert3(t0[j4], t1[j4], t2[j4], s);
                    }
                }
            }
        }
    }

    // merge across row-halves (lane^32; col = l31 preserved)
    #pragma unroll
    for (int j4 = 0; j4 < 4; ++j4) {
        float o0 = __shfl_xor(t0[j4], 32);
        float o1 = __shfl_xor(t1[j4], 32);
        float o2 = __shfl_xor(t2[j4], 32);
        insert3(t0[j4], t1[j4], t2[j4], o0);
        insert3(t0[j4], t1[j4], t2[j4], o1);
        insert3(t0[j4], t1[j4], t2[j4], o2);
    }
    if (h == 0) {
        #pragma unroll
        for (int j4 = 0; j4 < 4; ++j4) {
            int col = j4 * 32 + l31;
            red[w][col][0] = t0[j4];
            red[w][col][1] = t1[j4];
            red[w][col][2] = t2[j4];
        }
    }
    __syncthreads();
    if (tid < BN) {
        float a0 = red[0][tid][0], a1 = red[0][tid][1], a2 = red[0][tid][2];
        #pragma unroll
        for (int ww = 1; ww < 4; ++ww) {
            insert3(a0, a1, a2, red[ww][tid][0]);
            insert3(a0, a1, a2, red[ww][tid][1]);
            insert3(a0, a1, a2, red[ww][tid][2]);
        }
        float* dst = partials + ((size_t)(m0 + tid) * NSPLIT + sp) * 3;
        dst[0] = a0; dst[1] = a1; dst[2] = a2;
    }
}

// ---------------------------------------------------------------------------
// 4) merge partials, reduce q2 partials, sqrt, mean
__global__ __launch_bounds__(256) void merge_ood(const float* __restrict__ partials,
                                                 const float* __restrict__ q2p,
                                                 float* __restrict__ ood) {
    int m = blockIdx.x * 256 + threadIdx.x;
    if (m >= M) return;
    const float* pp = partials + (size_t)m * NSPLIT * 3;
    float a0 = INFINITY, a1 = INFINITY, a2 = INFINITY;
    #pragma unroll
    for (int j = 0; j < NSPLIT * 3; ++j) insert3(a0, a1, a2, pp[j]);
    const float* qp = q2p + (size_t)(m >> 7) * KSTEPS * 128 + (m & 127);
    float q = 0.f;
    #pragma unroll
    for (int g = 0; g < KSTEPS; ++g) q += qp[g * 128];
    float d0 = sqrtf(fmaxf(q + a0, 1e-12f));
    float d1 = sqrtf(fmaxf(q + a1, 1e-12f));
    float d2 = sqrtf(fmaxf(q + a2, 1e-12f));
    ood[m] = (d0 + d1 + d2) * (1.f / 3.f);
}

// ---------------------------------------------------------------------------
// 5) half-pixel bilinear 32x32 -> 512x512
__global__ __launch_bounds__(256) void upsample(const float* __restrict__ ood,
                                                float* __restrict__ out) {
    int idx = blockIdx.x * 256 + threadIdx.x;
    int ox = idx & (OUTW - 1);
    int oy = (idx >> 9) & (OUTH - 1);
    int bb = idx >> 18;
    float sx = (ox + 0.5f) * (32.f / OUTW) - 0.5f;
    float sy = (oy + 0.5f) * (32.f / OUTH) - 0.5f;
    float fx = floorf(sx), fy = floorf(sy);
    float wx = sx - fx, wy = sy - fy;
    int x0 = max(0, min(31, (int)fx));
    int x1 = max(0, min(31, (int)fx + 1));
    int y0 = max(0, min(31, (int)fy));
    int y1 = max(0, min(31, (int)fy + 1));
    const float* src = ood + bb * 1024;
    float v00 = src[y0 * 32 + x0];
    float v01 = src[y0 * 32 + x1];
    float v10 = src[y1 * 32 + x0];
    float v11 = src[y1 * 32 + x1];
    float top = v00 + wx * (v01 - v00);
    float bot = v10 + wx * (v11 - v10);
    out[idx] = top + wy * (bot - top);
}

// ---------------------------------------------------------------------------
extern "C" void kernel_launch(void* const* d_in, const int* in_sizes, int n_in,
                              void* d_out, int out_size, void* d_ws, size_t ws_size,
                              hipStream_t stream) {
    const float* emb = (const float*)d_in[0];
    const float* db  = (const float*)d_in[1];
    float* out = (float*)d_out;

    // workspace layout (bytes), total ~20.7 MB
    char* ws = (char*)d_ws;
    unsigned char* dbt8 = (unsigned char*)ws;                    // 158*12*8192 = 15,532,032
    unsigned char* qbt8 = (unsigned char*)(ws + 15532032);       // 32*12*8192  =  3,145,728
    float* x2p      = (float*)(ws + 18677760);                   // 158*12*128*4 = 970,752
    float* q2p      = (float*)(ws + 19648512);                   // 32*12*128*4 = 196,608
    float* ood      = (float*)(ws + 19845120);                   // 16,384
    float* partials = (float*)(ws + 19861504);                   // 4096*16*3*4 = 786,432

    db_convert<<<dim3(LT, KSTEPS), 256, 0, stream>>>(db, (uint4*)dbt8, x2p);
    q_convert<<<dim3(32, KSTEPS), 256, 0, stream>>>(emb, (uint4*)qbt8, q2p);
    gemm_topk<<<NSPLIT * 32, 256, 0, stream>>>(dbt8, qbt8, x2p, partials);
    merge_ood<<<(M + 255) / 256, 256, 0, stream>>>(partials, q2p, ood);
    upsample<<<(B * OUTH * OUTW) / 256, 256, 0, stream>>>(ood, out);
}